// Round 4
// baseline (223.192 us; speedup 1.0000x reference)
//
#include <hip/hip_runtime.h>
#include <math.h>

// ---------------- workspace layout (float offsets) ----------------
// Only the first 16 tokens per batch matter (E = HEAD = 16 slices the T axis).
#define WS_XN    0          // 64*1024                  LN'd x rows
#define WS_QKVP  65536      // 8 * 64*3072              split-K partials of q|k|v
#define WS_DIFF  1638400    // 1                        sum |ai1-ai0|
#define WS_AI1   1638404    // 64*1024                  iter-1 attention out
#define WS_AI2   1703940    // 64*1024                  iter-2 attention out
#define WS_WOP   1769476    // 8 * 64*1024              split-K partials of ai_sel @ Wo^T
#define WS_WT    2293764    // 3 * 4096                 WlqT|WlkT|WlvT  ([k][d] layout)
#define WS_QF    2306052    // 64*3072                  folded q|k|v (scale/bias applied)
// end: 2502660 floats = ~10 MB

__device__ __forceinline__ float4 f4zero() { return make_float4(0.f, 0.f, 0.f, 0.f); }
__device__ __forceinline__ float4 f4add(float4 a, float4 b) {
    return make_float4(a.x + b.x, a.y + b.y, a.z + b.z, a.w + b.w);
}
__device__ __forceinline__ float4 f4fma(float s, float4 a, float4 c) {
    return make_float4(fmaf(s, a.x, c.x), fmaf(s, a.y, c.y),
                       fmaf(s, a.z, c.z), fmaf(s, a.w, c.w));
}
__device__ __forceinline__ float dot4acc(float4 a, float4 b, float acc) {
    acc = fmaf(a.x, b.x, acc); acc = fmaf(a.y, b.y, acc);
    acc = fmaf(a.z, b.z, acc); acc = fmaf(a.w, b.w, acc);
    return acc;
}

// ---------------- K1: LayerNorm of 64 rows + weight transpose ----------------
__global__ __launch_bounds__(256) void k_ln(const float* __restrict__ x,
                                            const float* __restrict__ lna,
                                            const float* __restrict__ Wlq,
                                            const float* __restrict__ Wlk,
                                            const float* __restrict__ Wlv,
                                            float* __restrict__ xn,
                                            float* __restrict__ wt,
                                            float* __restrict__ diffg) {
    if (blockIdx.x >= 64) {
        int m = blockIdx.x - 64;
        const float* W = (m == 0) ? Wlq : (m == 1) ? Wlk : Wlv;
        float* dst = wt + m * 4096;
        for (int i = threadIdx.x; i < 4096; i += 256) {
            int k = i >> 6, d = i & 63;
            dst[i] = W[d * 64 + k];
        }
        return;
    }
    int r = blockIdx.x;                 // 0..63 = b*16 + t
    int b = r >> 4, t = r & 15;
    if (blockIdx.x == 0 && threadIdx.x == 0) diffg[0] = 0.f;
    const float* row = x + (size_t)(b * 2048 + t) * 1024;
    int tid = threadIdx.x;
    float4 xv = *(const float4*)&row[tid * 4];
    float s1 = xv.x + xv.y + xv.z + xv.w;
    float s2 = xv.x * xv.x + xv.y * xv.y + xv.z * xv.z + xv.w * xv.w;
    for (int off = 32; off; off >>= 1) {
        s1 += __shfl_xor(s1, off);
        s2 += __shfl_xor(s2, off);
    }
    __shared__ float ssum[4], ssq[4];
    int wv = tid >> 6, lane = tid & 63;
    if (lane == 0) { ssum[wv] = s1; ssq[wv] = s2; }
    __syncthreads();
    float tot = ssum[0] + ssum[1] + ssum[2] + ssum[3];
    float tq  = ssq[0] + ssq[1] + ssq[2] + ssq[3];
    float m   = tot * (1.0f / 1024.0f);
    float var = tq * (1.0f / 1024.0f) - m * m;
    float rs  = rsqrtf(var + 1e-5f);
    float4 w4 = *(const float4*)&lna[tid * 4];
    float4 o  = make_float4((xv.x - m) * rs * w4.x, (xv.y - m) * rs * w4.y,
                            (xv.z - m) * rs * w4.z, (xv.w - m) * rs * w4.w);
    *(float4*)&xn[r * 1024 + tid * 4] = o;
}

// ---------------- K2: q|k|v = xn @ [Wq|Wk|Wv]^T, split-K partials ----------------
__global__ __launch_bounds__(256) void k_qkv(const float* __restrict__ xn,
                                             const float* __restrict__ Wq,
                                             const float* __restrict__ Wk,
                                             const float* __restrict__ Wv,
                                             float* __restrict__ qkvp) {
    int ct  = blockIdx.x;               // 0..95
    int ksl = blockIdx.y;               // 0..7
    int m   = ct >> 5;
    const float* W = (m == 0) ? Wq : (m == 1) ? Wk : Wv;
    int j0 = (ct & 31) * 32;
    int k0 = ksl * 128;
    __shared__ float At[64][132];
    __shared__ float Bt[32][132];
    int tid = threadIdx.x;
    for (int i = tid; i < 2048; i += 256) {
        int r = i >> 5, kk = (i & 31) << 2;
        *(float4*)&At[r][kk] = *(const float4*)&xn[r * 1024 + k0 + kk];
    }
    for (int i = tid; i < 1024; i += 256) {
        int r = i >> 5, kk = (i & 31) << 2;
        *(float4*)&Bt[r][kk] = *(const float4*)&W[(size_t)(j0 + r) * 1024 + k0 + kk];
    }
    __syncthreads();
    int rg = tid >> 4, cg = tid & 15;
    float acc[4][2];
#pragma unroll
    for (int i = 0; i < 4; i++) { acc[i][0] = 0.f; acc[i][1] = 0.f; }
    for (int k = 0; k < 128; k += 4) {
        float4 b0 = *(float4*)&Bt[cg * 2 + 0][k];
        float4 b1 = *(float4*)&Bt[cg * 2 + 1][k];
#pragma unroll
        for (int i = 0; i < 4; i++) {
            float4 a = *(float4*)&At[rg * 4 + i][k];
            acc[i][0] = dot4acc(a, b0, acc[i][0]);
            acc[i][1] = dot4acc(a, b1, acc[i][1]);
        }
    }
    float* dst = qkvp + (size_t)ksl * 196608;
    int colg = ct * 32 + cg * 2;
#pragma unroll
    for (int i = 0; i < 4; i++) {
        *(float2*)&dst[(rg * 4 + i) * 3072 + colg] = make_float2(acc[i][0], acc[i][1]);
    }
}

// ---------------- K2b: fold split-K partials, apply scale/bias ----------------
__global__ __launch_bounds__(256) void k_fold(const float* __restrict__ qkvp,
                                              const float* __restrict__ bq,
                                              const float* __restrict__ bv,
                                              float* __restrict__ qf) {
    int m   = blockIdx.x;               // 0=q, 1=k, 2=v
    int row = blockIdx.y;
    int cc  = threadIdx.x * 4;
    int col = m * 1024 + cc;
    float4 s = f4zero();
#pragma unroll
    for (int sl = 0; sl < 8; sl++)
        s = f4add(s, *(const float4*)&qkvp[(size_t)sl * 196608 + row * 3072 + col]);
    const float SCALE = 0.35355339059327378f;   // 64^-0.25
    if (m == 0) {
        float4 b = *(const float4*)&bq[cc];
        s = make_float4((s.x + b.x) * SCALE, (s.y + b.y) * SCALE,
                        (s.z + b.z) * SCALE, (s.w + b.w) * SCALE);
    } else if (m == 1) {
        s = make_float4(s.x * SCALE, s.y * SCALE, s.z * SCALE, s.w * SCALE);
    } else {
        float4 b = *(const float4*)&bv[cc];
        s = f4add(s, b);
    }
    *(float4*)&qf[row * 3072 + col] = s;
}

// ---------------- K3: 3-iteration loop, one block per (b,h) ----------------
// KEY CHANGE vs R3: weight tiles are loop-invariant -> preload each GEMM
// wave's full 16 KB tile into REGISTERS once (wreg[64] float4, 64 independent
// global loads, pipelined). launch_bounds(256,1) unlocks the VGPR budget
// (~300 regs; only 1 block/CU needed). The k-loop is then 1 ds_read_b128 +
// 16 FMA per step -- no global latency on the critical path.
__global__ __launch_bounds__(256, 1) void k_iter(
        const float* __restrict__ qf, const float* __restrict__ wt,
        const float* __restrict__ lnc, const float* __restrict__ lnd,
        const float* __restrict__ blq, const float* __restrict__ blk_,
        const float* __restrict__ blv, const float* __restrict__ temp,
        float* __restrict__ ai1g, float* __restrict__ ai2g,
        float* __restrict__ diffg) {
    __shared__ __align__(16) float qcT[64 * 20];   // [d-or-k][t] stride 20
    __shared__ __align__(16) float kcT[64 * 20];
    __shared__ __align__(16) float vcT[64 * 20];
    __shared__ __align__(16) float qsR[16 * 68];   // row-major [t][d]
    __shared__ __align__(16) float ksR[16 * 68];
    __shared__ __align__(16) float vlR[16 * 68];
    __shared__ float dred[4];

    int tid  = threadIdx.x;
    int b    = blockIdx.x >> 4, h = blockIdx.x & 15;
    int wv   = tid >> 6, lane = tid & 63;
    float tempv = temp[0];

    int tq = lane >> 4, dq = lane & 15;     // P1 tile coords
    int t2 = tid >> 4,  u  = tid & 15;      // P2 coords
    int rowi2 = b * 16 + t2, col2 = h * 64 + u * 4;

    // ---- staging loads (3 float4 per thread)
    const float* R = qf + rowi2 * 3072 + h * 64 + u * 4;
    float4 q4 = *(const float4*)&R[0];
    float4 k4 = *(const float4*)&R[1024];
    float4 v4 = *(const float4*)&R[2048];

    // ---- one-time register preload of this wave's weight tile [k][4dq..]
    const float* WT = (wv == 0) ? wt : (wv == 1) ? wt + 4096 : wt + 8192;
    float4 wreg[64];
#pragma unroll
    for (int k = 0; k < 64; ++k)
        wreg[k] = *(const float4*)&WT[k * 64 + 4 * dq];

    // ---- staging stores (transposed)
    {
        float qv[4] = { q4.x, q4.y, q4.z, q4.w };
        float kv[4] = { k4.x, k4.y, k4.z, k4.w };
        float vv[4] = { v4.x, v4.y, v4.z, v4.w };
#pragma unroll
        for (int c = 0; c < 4; c++) {
            qcT[(u * 4 + c) * 20 + t2] = qv[c];
            kcT[(u * 4 + c) * 20 + t2] = kv[c];
            vcT[(u * 4 + c) * 20 + t2] = vv[c];
        }
    }
    __syncthreads();

    float4 ai0 = f4zero();
    float  dlocal = 0.f;

#pragma unroll 1
    for (int it = 0; it < 3; ++it) {
        float t_it = tempv + 0.005f * (float)it;
        float tsc  = (t_it != 1.0f && t_it > 0.0f) ? rsqrtf(t_it) : 1.0f;

        // ---------------- P1: three GEMMs, wave-specialized ----------------
        if (wv == 0) {
            float acc[4][4];
#pragma unroll
            for (int i = 0; i < 4; i++)
#pragma unroll
                for (int j = 0; j < 4; j++) acc[i][j] = 0.f;
#pragma unroll
            for (int k = 0; k < 64; ++k) {
                float4 a4 = *(float4*)&qcT[k * 20 + 4 * tq];
                float4 b4 = wreg[k];
                float av[4] = { a4.x, a4.y, a4.z, a4.w };
#pragma unroll
                for (int i = 0; i < 4; i++) {
                    acc[i][0] = fmaf(av[i], b4.x, acc[i][0]);
                    acc[i][1] = fmaf(av[i], b4.y, acc[i][1]);
                    acc[i][2] = fmaf(av[i], b4.z, acc[i][2]);
                    acc[i][3] = fmaf(av[i], b4.w, acc[i][3]);
                }
            }
            float4 bb = *(const float4*)&blq[4 * dq];
            float4 lw = *(const float4*)&lnc[4 * dq];
#pragma unroll
            for (int i = 0; i < 4; i++) {
                acc[i][0] += bb.x; acc[i][1] += bb.y;
                acc[i][2] += bb.z; acc[i][3] += bb.w;
                float s1 = acc[i][0] + acc[i][1] + acc[i][2] + acc[i][3];
                float s2 = acc[i][0]*acc[i][0] + acc[i][1]*acc[i][1]
                         + acc[i][2]*acc[i][2] + acc[i][3]*acc[i][3];
                for (int off = 8; off; off >>= 1) {
                    s1 += __shfl_xor(s1, off); s2 += __shfl_xor(s2, off);
                }
                float m  = s1 * (1.0f / 64.0f);
                float vr = s2 * (1.0f / 64.0f) - m * m;
                float rs = rsqrtf(vr + 1e-5f) * tsc;
                float4 o = make_float4((acc[i][0] - m) * rs * lw.x,
                                       (acc[i][1] - m) * rs * lw.y,
                                       (acc[i][2] - m) * rs * lw.z,
                                       (acc[i][3] - m) * rs * lw.w);
                *(float4*)&qsR[(4 * tq + i) * 68 + 4 * dq] = o;
            }
        } else if (wv == 1) {
            float acc[4][4];
#pragma unroll
            for (int i = 0; i < 4; i++)
#pragma unroll
                for (int j = 0; j < 4; j++) acc[i][j] = 0.f;
#pragma unroll
            for (int k = 0; k < 64; ++k) {
                float4 a4 = *(float4*)&kcT[k * 20 + 4 * tq];
                float4 b4 = wreg[k];
                float av[4] = { a4.x, a4.y, a4.z, a4.w };
#pragma unroll
                for (int i = 0; i < 4; i++) {
                    acc[i][0] = fmaf(av[i], b4.x, acc[i][0]);
                    acc[i][1] = fmaf(av[i], b4.y, acc[i][1]);
                    acc[i][2] = fmaf(av[i], b4.z, acc[i][2]);
                    acc[i][3] = fmaf(av[i], b4.w, acc[i][3]);
                }
            }
            float4 bb = *(const float4*)&blk_[4 * dq];
#pragma unroll
            for (int i = 0; i < 4; i++) {
                acc[i][0] += bb.x; acc[i][1] += bb.y;
                acc[i][2] += bb.z; acc[i][3] += bb.w;
            }
#pragma unroll
            for (int j = 0; j < 4; j++) {
                float4 cv = make_float4(acc[0][j], acc[1][j], acc[2][j], acc[3][j]);
                *(float4*)&kcT[(4 * dq + j) * 20 + 4 * tq] = cv;
            }
            float4 lw = *(const float4*)&lnd[4 * dq];
#pragma unroll
            for (int i = 0; i < 4; i++) {
                float s1 = acc[i][0] + acc[i][1] + acc[i][2] + acc[i][3];
                float s2 = acc[i][0]*acc[i][0] + acc[i][1]*acc[i][1]
                         + acc[i][2]*acc[i][2] + acc[i][3]*acc[i][3];
                for (int off = 8; off; off >>= 1) {
                    s1 += __shfl_xor(s1, off); s2 += __shfl_xor(s2, off);
                }
                float m  = s1 * (1.0f / 64.0f);
                float vr = s2 * (1.0f / 64.0f) - m * m;
                float rs = rsqrtf(vr + 1e-5f);
                float4 o = make_float4((acc[i][0] - m) * rs * lw.x,
                                       (acc[i][1] - m) * rs * lw.y,
                                       (acc[i][2] - m) * rs * lw.z,
                                       (acc[i][3] - m) * rs * lw.w);
                *(float4*)&ksR[(4 * tq + i) * 68 + 4 * dq] = o;
            }
        } else if (wv == 2) {
            float acc[4][4];
#pragma unroll
            for (int i = 0; i < 4; i++)
#pragma unroll
                for (int j = 0; j < 4; j++) acc[i][j] = 0.f;
#pragma unroll
            for (int k = 0; k < 64; ++k) {
                float4 a4 = *(float4*)&vcT[k * 20 + 4 * tq];
                float4 b4 = wreg[k];
                float av[4] = { a4.x, a4.y, a4.z, a4.w };
#pragma unroll
                for (int i = 0; i < 4; i++) {
                    acc[i][0] = fmaf(av[i], b4.x, acc[i][0]);
                    acc[i][1] = fmaf(av[i], b4.y, acc[i][1]);
                    acc[i][2] = fmaf(av[i], b4.z, acc[i][2]);
                    acc[i][3] = fmaf(av[i], b4.w, acc[i][3]);
                }
            }
            float4 bb = *(const float4*)&blv[4 * dq];
#pragma unroll
            for (int i = 0; i < 4; i++) {
                acc[i][0] += bb.x; acc[i][1] += bb.y;
                acc[i][2] += bb.z; acc[i][3] += bb.w;
                *(float4*)&vlR[(4 * tq + i) * 68 + 4 * dq] =
                    make_float4(acc[i][0], acc[i][1], acc[i][2], acc[i][3]);
            }
#pragma unroll
            for (int j = 0; j < 4; j++) {
                float4 cv = make_float4(acc[0][j], acc[1][j], acc[2][j], acc[3][j]);
                *(float4*)&vcT[(4 * dq + j) * 20 + 4 * tq] = cv;
            }
        }
        __syncthreads();

        // ---------------- P2: logits + softmax + P@vl (all waves) ----------
        float lg = 0.f;
#pragma unroll
        for (int c = 0; c < 16; ++c) {
            float4 a4 = *(float4*)&qsR[t2 * 68 + 4 * c];
            float4 b4 = *(float4*)&ksR[u  * 68 + 4 * c];
            lg = dot4acc(a4, b4, lg);
        }
        lg *= 0.125f;                        // 1/sqrt(64)
        float mx = lg;
        for (int off = 8; off; off >>= 1) mx = fmaxf(mx, __shfl_xor(mx, off));
        float e = __expf(lg - mx);
        float sm = e;
        for (int off = 8; off; off >>= 1) sm += __shfl_xor(sm, off);
        float p = e / sm;

        float4 ai = f4zero();
        int gbase = lane & 48;
#pragma unroll
        for (int tk = 0; tk < 16; ++tk) {
            float pk = __shfl(p, gbase + tk);
            ai = f4fma(pk, *(float4*)&vlR[tk * 68 + 4 * u], ai);
        }

        if (it == 0) {
            ai0 = ai;
        } else if (it == 1) {
            dlocal = fabsf(ai.x - ai0.x) + fabsf(ai.y - ai0.y) +
                     fabsf(ai.z - ai0.z) + fabsf(ai.w - ai0.w);
            *(float4*)&ai1g[rowi2 * 1024 + col2] = ai;
        } else {
            *(float4*)&ai2g[rowi2 * 1024 + col2] = ai;
        }
        qcT[(4 * u + 0) * 20 + t2] += ai.x;
        qcT[(4 * u + 1) * 20 + t2] += ai.y;
        qcT[(4 * u + 2) * 20 + t2] += ai.z;
        qcT[(4 * u + 3) * 20 + t2] += ai.w;
        __syncthreads();
    }

    float ds = dlocal;
    for (int off = 32; off; off >>= 1) ds += __shfl_xor(ds, off);
    if (lane == 0) dred[wv] = ds;
    __syncthreads();
    if (tid == 0) atomicAdd(diffg, dred[0] + dred[1] + dred[2] + dred[3]);
}

// ---------------- K4: ai_sel @ Wo^T, split-K partials ----------------
__global__ __launch_bounds__(256) void k_wo(const float* __restrict__ ai1g,
                                            const float* __restrict__ ai2g,
                                            const float* __restrict__ diffg,
                                            const float* __restrict__ thrp,
                                            const float* __restrict__ facp,
                                            const float* __restrict__ Wo,
                                            float* __restrict__ wop) {
    float diff = diffg[0] * (1.0f / 8388608.0f);
    const float* A = (diff < thrp[0] + facp[0] * diff) ? ai1g : ai2g;
    int jt  = blockIdx.x;
    int ksl = blockIdx.y;
    int k0  = ksl * 128;
    __shared__ float At[64][132];
    __shared__ float Bt[32][132];
    int tid = threadIdx.x;
    for (int i = tid; i < 2048; i += 256) {
        int r = i >> 5, kk = (i & 31) << 2;
        *(float4*)&At[r][kk] = *(const float4*)&A[r * 1024 + k0 + kk];
    }
    for (int i = tid; i < 1024; i += 256) {
        int r = i >> 5, kk = (i & 31) << 2;
        *(float4*)&Bt[r][kk] = *(const float4*)&Wo[(size_t)(jt * 32 + r) * 1024 + k0 + kk];
    }
    __syncthreads();
    int rg = tid >> 4, cg = tid & 15;
    float acc[4][2];
#pragma unroll
    for (int i = 0; i < 4; i++) { acc[i][0] = 0.f; acc[i][1] = 0.f; }
    for (int k = 0; k < 128; k += 4) {
        float4 b0 = *(float4*)&Bt[cg * 2 + 0][k];
        float4 b1 = *(float4*)&Bt[cg * 2 + 1][k];
#pragma unroll
        for (int i = 0; i < 4; i++) {
            float4 a = *(float4*)&At[rg * 4 + i][k];
            acc[i][0] = dot4acc(a, b0, acc[i][0]);
            acc[i][1] = dot4acc(a, b1, acc[i][1]);
        }
    }
    float* dst = wop + (size_t)ksl * 65536;
    int colg = jt * 32 + cg * 2;
#pragma unroll
    for (int i = 0; i < 4; i++) {
        *(float2*)&dst[(rg * 4 + i) * 1024 + colg] = make_float2(acc[i][0], acc[i][1]);
    }
}

// ---------------- K5: final output write ----------------
__global__ __launch_bounds__(256) void k_bo(const float* __restrict__ bo,
                                            const float* __restrict__ wop,
                                            float* __restrict__ out) {
    int row = blockIdx.x;
    int tid = threadIdx.x;
    int b = row >> 11, t = row & 2047;
    float4 o = *(const float4*)&bo[tid * 4];
    if (t < 16) {
        int ri = b * 16 + t;
#pragma unroll
        for (int s = 0; s < 8; s++) {
            float4 p = *(const float4*)&wop[(size_t)s * 65536 + ri * 1024 + tid * 4];
            o = f4add(o, p);
        }
    }
    *(float4*)&out[(size_t)row * 1024 + tid * 4] = o;
}

extern "C" void kernel_launch(void* const* d_in, const int* in_sizes, int n_in,
                              void* d_out, int out_size, void* d_ws, size_t ws_size,
                              hipStream_t stream) {
    (void)in_sizes; (void)n_in; (void)out_size; (void)ws_size;
    const float* x    = (const float*)d_in[0];
    const float* Wq   = (const float*)d_in[1];
    const float* bq   = (const float*)d_in[2];
    const float* Wk   = (const float*)d_in[3];
    const float* Wv   = (const float*)d_in[4];
    const float* bv   = (const float*)d_in[5];
    const float* Wo   = (const float*)d_in[6];
    const float* bo   = (const float*)d_in[7];
    const float* lna  = (const float*)d_in[8];
    const float* lnc  = (const float*)d_in[9];
    const float* lnd  = (const float*)d_in[10];
    const float* Wlq  = (const float*)d_in[11];
    const float* blq  = (const float*)d_in[12];
    const float* Wlk  = (const float*)d_in[13];
    const float* blk_ = (const float*)d_in[14];
    const float* Wlv  = (const float*)d_in[15];
    const float* blv  = (const float*)d_in[16];
    const float* temp = (const float*)d_in[17];
    const float* thr  = (const float*)d_in[18];
    const float* fac  = (const float*)d_in[19];
    float* ws  = (float*)d_ws;
    float* out = (float*)d_out;

    k_ln  <<<67, 256, 0, stream>>>(x, lna, Wlq, Wlk, Wlv,
                                   ws + WS_XN, ws + WS_WT, ws + WS_DIFF);
    k_qkv <<<dim3(96, 8), 256, 0, stream>>>(ws + WS_XN, Wq, Wk, Wv, ws + WS_QKVP);
    k_fold<<<dim3(3, 64), 256, 0, stream>>>(ws + WS_QKVP, bq, bv, ws + WS_QF);
    k_iter<<<64, 256, 0, stream>>>(ws + WS_QF, ws + WS_WT, lnc, lnd,
                                   blq, blk_, blv, temp,
                                   ws + WS_AI1, ws + WS_AI2, ws + WS_DIFF);
    k_wo  <<<dim3(32, 8), 256, 0, stream>>>(ws + WS_AI1, ws + WS_AI2, ws + WS_DIFF,
                                            thr, fac, Wo, ws + WS_WOP);
    k_bo  <<<8192, 256, 0, stream>>>(bo, ws + WS_WOP, out);
}

// Round 5
// 207.502 us; speedup vs baseline: 1.0756x; 1.0756x over previous
//
#include <hip/hip_runtime.h>
#include <math.h>

// ---------------- workspace layout (float offsets) ----------------
// Only the first 16 tokens per batch matter (E = HEAD = 16 slices the T axis).
#define WS_XN    0          // 64*1024                  LN'd x rows
#define WS_QKVP  65536      // 8 * 64*3072              split-K partials of q|k|v
#define WS_DIFF  1638400    // 1                        sum |ai1-ai0|
#define WS_AI1   1638404    // 64*1024                  iter-1 attention out
#define WS_AI2   1703940    // 64*1024                  iter-2 attention out
#define WS_WOP   1769476    // 8 * 64*1024              split-K partials of ai_sel @ Wo^T
#define WS_WT    2293764    // 3 * 4096                 WlqT|WlkT|WlvT  ([k][d] layout)
#define WS_QF    2306052    // 64*3072                  folded q|k|v (scale/bias applied)
// end: 2502660 floats = ~10 MB

__device__ __forceinline__ float4 f4zero() { return make_float4(0.f, 0.f, 0.f, 0.f); }
__device__ __forceinline__ float4 f4add(float4 a, float4 b) {
    return make_float4(a.x + b.x, a.y + b.y, a.z + b.z, a.w + b.w);
}
__device__ __forceinline__ float4 f4fma(float s, float4 a, float4 c) {
    return make_float4(fmaf(s, a.x, c.x), fmaf(s, a.y, c.y),
                       fmaf(s, a.z, c.z), fmaf(s, a.w, c.w));
}
__device__ __forceinline__ float dot4acc(float4 a, float4 b, float acc) {
    acc = fmaf(a.x, b.x, acc); acc = fmaf(a.y, b.y, acc);
    acc = fmaf(a.z, b.z, acc); acc = fmaf(a.w, b.w, acc);
    return acc;
}

// 16x64 @ 64x64 GEMM inner loop: LDS A ([k][t] stride 20), global B ([k][d]).
// Weight loads double-buffered in registers, 8 float4 per batch (8 loads in
// flight -> latency amortized; 2x8x4=64 VGPRs for buffers, fits under 256).
__device__ __forceinline__ void gemm_16x64(const float* __restrict__ ldsA, int tq,
                                           const float* __restrict__ WT, int dq,
                                           float acc[4][4]) {
    float4 wA[8];
#pragma unroll
    for (int j = 0; j < 8; ++j)
        wA[j] = *(const float4*)&WT[j * 64 + 4 * dq];
#pragma unroll
    for (int kb = 0; kb < 64; kb += 8) {
        float4 wB[8];
        if (kb + 8 < 64) {
#pragma unroll
            for (int j = 0; j < 8; ++j)
                wB[j] = *(const float4*)&WT[(kb + 8 + j) * 64 + 4 * dq];
        }
#pragma unroll
        for (int j = 0; j < 8; ++j) {
            float4 a4 = *(const float4*)&ldsA[(kb + j) * 20 + 4 * tq];
            float4 b4 = wA[j];
            float av[4] = { a4.x, a4.y, a4.z, a4.w };
#pragma unroll
            for (int i = 0; i < 4; i++) {
                acc[i][0] = fmaf(av[i], b4.x, acc[i][0]);
                acc[i][1] = fmaf(av[i], b4.y, acc[i][1]);
                acc[i][2] = fmaf(av[i], b4.z, acc[i][2]);
                acc[i][3] = fmaf(av[i], b4.w, acc[i][3]);
            }
        }
        if (kb + 8 < 64) {
#pragma unroll
            for (int j = 0; j < 8; ++j) wA[j] = wB[j];
        }
    }
}

// ---------------- K1: LayerNorm of 64 rows + weight transpose ----------------
__global__ __launch_bounds__(256) void k_ln(const float* __restrict__ x,
                                            const float* __restrict__ lna,
                                            const float* __restrict__ Wlq,
                                            const float* __restrict__ Wlk,
                                            const float* __restrict__ Wlv,
                                            float* __restrict__ xn,
                                            float* __restrict__ wt,
                                            float* __restrict__ diffg) {
    if (blockIdx.x >= 64) {
        int m = blockIdx.x - 64;
        const float* W = (m == 0) ? Wlq : (m == 1) ? Wlk : Wlv;
        float* dst = wt + m * 4096;
        for (int i = threadIdx.x; i < 4096; i += 256) {
            int k = i >> 6, d = i & 63;
            dst[i] = W[d * 64 + k];
        }
        return;
    }
    int r = blockIdx.x;                 // 0..63 = b*16 + t
    int b = r >> 4, t = r & 15;
    if (blockIdx.x == 0 && threadIdx.x == 0) diffg[0] = 0.f;
    const float* row = x + (size_t)(b * 2048 + t) * 1024;
    int tid = threadIdx.x;
    float4 xv = *(const float4*)&row[tid * 4];
    float s1 = xv.x + xv.y + xv.z + xv.w;
    float s2 = xv.x * xv.x + xv.y * xv.y + xv.z * xv.z + xv.w * xv.w;
    for (int off = 32; off; off >>= 1) {
        s1 += __shfl_xor(s1, off);
        s2 += __shfl_xor(s2, off);
    }
    __shared__ float ssum[4], ssq[4];
    int wv = tid >> 6, lane = tid & 63;
    if (lane == 0) { ssum[wv] = s1; ssq[wv] = s2; }
    __syncthreads();
    float tot = ssum[0] + ssum[1] + ssum[2] + ssum[3];
    float tq  = ssq[0] + ssq[1] + ssq[2] + ssq[3];
    float m   = tot * (1.0f / 1024.0f);
    float var = tq * (1.0f / 1024.0f) - m * m;
    float rs  = rsqrtf(var + 1e-5f);
    float4 w4 = *(const float4*)&lna[tid * 4];
    float4 o  = make_float4((xv.x - m) * rs * w4.x, (xv.y - m) * rs * w4.y,
                            (xv.z - m) * rs * w4.z, (xv.w - m) * rs * w4.w);
    *(float4*)&xn[r * 1024 + tid * 4] = o;
}

// ---------------- K2: q|k|v = xn @ [Wq|Wk|Wv]^T, split-K partials ----------------
__global__ __launch_bounds__(256) void k_qkv(const float* __restrict__ xn,
                                             const float* __restrict__ Wq,
                                             const float* __restrict__ Wk,
                                             const float* __restrict__ Wv,
                                             float* __restrict__ qkvp) {
    int ct  = blockIdx.x;               // 0..95
    int ksl = blockIdx.y;               // 0..7
    int m   = ct >> 5;
    const float* W = (m == 0) ? Wq : (m == 1) ? Wk : Wv;
    int j0 = (ct & 31) * 32;
    int k0 = ksl * 128;
    __shared__ float At[64][132];
    __shared__ float Bt[32][132];
    int tid = threadIdx.x;
    for (int i = tid; i < 2048; i += 256) {
        int r = i >> 5, kk = (i & 31) << 2;
        *(float4*)&At[r][kk] = *(const float4*)&xn[r * 1024 + k0 + kk];
    }
    for (int i = tid; i < 1024; i += 256) {
        int r = i >> 5, kk = (i & 31) << 2;
        *(float4*)&Bt[r][kk] = *(const float4*)&W[(size_t)(j0 + r) * 1024 + k0 + kk];
    }
    __syncthreads();
    int rg = tid >> 4, cg = tid & 15;
    float acc[4][2];
#pragma unroll
    for (int i = 0; i < 4; i++) { acc[i][0] = 0.f; acc[i][1] = 0.f; }
    for (int k = 0; k < 128; k += 4) {
        float4 b0 = *(float4*)&Bt[cg * 2 + 0][k];
        float4 b1 = *(float4*)&Bt[cg * 2 + 1][k];
#pragma unroll
        for (int i = 0; i < 4; i++) {
            float4 a = *(float4*)&At[rg * 4 + i][k];
            acc[i][0] = dot4acc(a, b0, acc[i][0]);
            acc[i][1] = dot4acc(a, b1, acc[i][1]);
        }
    }
    float* dst = qkvp + (size_t)ksl * 196608;
    int colg = ct * 32 + cg * 2;
#pragma unroll
    for (int i = 0; i < 4; i++) {
        *(float2*)&dst[(rg * 4 + i) * 3072 + colg] = make_float2(acc[i][0], acc[i][1]);
    }
}

// ---------------- K2b: fold split-K partials, apply scale/bias ----------------
__global__ __launch_bounds__(256) void k_fold(const float* __restrict__ qkvp,
                                              const float* __restrict__ bq,
                                              const float* __restrict__ bv,
                                              float* __restrict__ qf) {
    int m   = blockIdx.x;               // 0=q, 1=k, 2=v
    int row = blockIdx.y;
    int cc  = threadIdx.x * 4;
    int col = m * 1024 + cc;
    float4 s = f4zero();
#pragma unroll
    for (int sl = 0; sl < 8; sl++)
        s = f4add(s, *(const float4*)&qkvp[(size_t)sl * 196608 + row * 3072 + col]);
    const float SCALE = 0.35355339059327378f;   // 64^-0.25
    if (m == 0) {
        float4 b = *(const float4*)&bq[cc];
        s = make_float4((s.x + b.x) * SCALE, (s.y + b.y) * SCALE,
                        (s.z + b.z) * SCALE, (s.w + b.w) * SCALE);
    } else if (m == 1) {
        s = make_float4(s.x * SCALE, s.y * SCALE, s.z * SCALE, s.w * SCALE);
    } else {
        float4 b = *(const float4*)&bv[cc];
        s = f4add(s, b);
    }
    *(float4*)&qf[row * 3072 + col] = s;
}

// ---------------- K3: 3-iteration loop, one block per (b,h) ----------------
// Weights streamed from global wt (L1/L2-hot) with register double-buffered
// 8-wide batches (gemm_16x64). launch_bounds(256,2): VGPR cap 256, target
// ~130-180 actual -- NO spill (R4's wreg[64] preload spilled at the 256 cap).
__global__ __launch_bounds__(256, 2) void k_iter(
        const float* __restrict__ qf, const float* __restrict__ wt,
        const float* __restrict__ lnc, const float* __restrict__ lnd,
        const float* __restrict__ blq, const float* __restrict__ blk_,
        const float* __restrict__ blv, const float* __restrict__ temp,
        float* __restrict__ ai1g, float* __restrict__ ai2g,
        float* __restrict__ diffg) {
    __shared__ __align__(16) float qcT[64 * 20];   // [d-or-k][t] stride 20
    __shared__ __align__(16) float kcT[64 * 20];
    __shared__ __align__(16) float vcT[64 * 20];
    __shared__ __align__(16) float qsR[16 * 68];   // row-major [t][d]
    __shared__ __align__(16) float ksR[16 * 68];
    __shared__ __align__(16) float vlR[16 * 68];
    __shared__ float dred[4];

    int tid  = threadIdx.x;
    int b    = blockIdx.x >> 4, h = blockIdx.x & 15;
    int wv   = tid >> 6, lane = tid & 63;
    float tempv = temp[0];

    int tq = lane >> 4, dq = lane & 15;     // P1 tile coords
    int t2 = tid >> 4,  u  = tid & 15;      // P2 coords
    int rowi2 = b * 16 + t2, col2 = h * 64 + u * 4;

    // ---- staging loads (3 float4 per thread)
    const float* R = qf + rowi2 * 3072 + h * 64 + u * 4;
    float4 q4 = *(const float4*)&R[0];
    float4 k4 = *(const float4*)&R[1024];
    float4 v4 = *(const float4*)&R[2048];
    {
        float qv[4] = { q4.x, q4.y, q4.z, q4.w };
        float kv[4] = { k4.x, k4.y, k4.z, k4.w };
        float vv[4] = { v4.x, v4.y, v4.z, v4.w };
#pragma unroll
        for (int c = 0; c < 4; c++) {
            qcT[(u * 4 + c) * 20 + t2] = qv[c];
            kcT[(u * 4 + c) * 20 + t2] = kv[c];
            vcT[(u * 4 + c) * 20 + t2] = vv[c];
        }
    }
    __syncthreads();

    float4 ai0 = f4zero();
    float  dlocal = 0.f;

#pragma unroll 1
    for (int it = 0; it < 3; ++it) {
        float t_it = tempv + 0.005f * (float)it;
        float tsc  = (t_it != 1.0f && t_it > 0.0f) ? rsqrtf(t_it) : 1.0f;

        // ---------------- P1: three GEMMs, wave-specialized ----------------
        if (wv == 0) {
            float acc[4][4];
#pragma unroll
            for (int i = 0; i < 4; i++)
#pragma unroll
                for (int j = 0; j < 4; j++) acc[i][j] = 0.f;
            gemm_16x64(qcT, tq, wt, dq, acc);
            float4 bb = *(const float4*)&blq[4 * dq];
            float4 lw = *(const float4*)&lnc[4 * dq];
#pragma unroll
            for (int i = 0; i < 4; i++) {
                acc[i][0] += bb.x; acc[i][1] += bb.y;
                acc[i][2] += bb.z; acc[i][3] += bb.w;
                float s1 = acc[i][0] + acc[i][1] + acc[i][2] + acc[i][3];
                float s2 = acc[i][0]*acc[i][0] + acc[i][1]*acc[i][1]
                         + acc[i][2]*acc[i][2] + acc[i][3]*acc[i][3];
                for (int off = 8; off; off >>= 1) {
                    s1 += __shfl_xor(s1, off); s2 += __shfl_xor(s2, off);
                }
                float m  = s1 * (1.0f / 64.0f);
                float vr = s2 * (1.0f / 64.0f) - m * m;
                float rs = rsqrtf(vr + 1e-5f) * tsc;
                float4 o = make_float4((acc[i][0] - m) * rs * lw.x,
                                       (acc[i][1] - m) * rs * lw.y,
                                       (acc[i][2] - m) * rs * lw.z,
                                       (acc[i][3] - m) * rs * lw.w);
                *(float4*)&qsR[(4 * tq + i) * 68 + 4 * dq] = o;
            }
        } else if (wv == 1) {
            float acc[4][4];
#pragma unroll
            for (int i = 0; i < 4; i++)
#pragma unroll
                for (int j = 0; j < 4; j++) acc[i][j] = 0.f;
            gemm_16x64(kcT, tq, wt + 4096, dq, acc);
            float4 bb = *(const float4*)&blk_[4 * dq];
#pragma unroll
            for (int i = 0; i < 4; i++) {
                acc[i][0] += bb.x; acc[i][1] += bb.y;
                acc[i][2] += bb.z; acc[i][3] += bb.w;
            }
#pragma unroll
            for (int j = 0; j < 4; j++) {
                float4 cv = make_float4(acc[0][j], acc[1][j], acc[2][j], acc[3][j]);
                *(float4*)&kcT[(4 * dq + j) * 20 + 4 * tq] = cv;
            }
            float4 lw = *(const float4*)&lnd[4 * dq];
#pragma unroll
            for (int i = 0; i < 4; i++) {
                float s1 = acc[i][0] + acc[i][1] + acc[i][2] + acc[i][3];
                float s2 = acc[i][0]*acc[i][0] + acc[i][1]*acc[i][1]
                         + acc[i][2]*acc[i][2] + acc[i][3]*acc[i][3];
                for (int off = 8; off; off >>= 1) {
                    s1 += __shfl_xor(s1, off); s2 += __shfl_xor(s2, off);
                }
                float m  = s1 * (1.0f / 64.0f);
                float vr = s2 * (1.0f / 64.0f) - m * m;
                float rs = rsqrtf(vr + 1e-5f);
                float4 o = make_float4((acc[i][0] - m) * rs * lw.x,
                                       (acc[i][1] - m) * rs * lw.y,
                                       (acc[i][2] - m) * rs * lw.z,
                                       (acc[i][3] - m) * rs * lw.w);
                *(float4*)&ksR[(4 * tq + i) * 68 + 4 * dq] = o;
            }
        } else if (wv == 2) {
            float acc[4][4];
#pragma unroll
            for (int i = 0; i < 4; i++)
#pragma unroll
                for (int j = 0; j < 4; j++) acc[i][j] = 0.f;
            gemm_16x64(vcT, tq, wt + 8192, dq, acc);
            float4 bb = *(const float4*)&blv[4 * dq];
#pragma unroll
            for (int i = 0; i < 4; i++) {
                acc[i][0] += bb.x; acc[i][1] += bb.y;
                acc[i][2] += bb.z; acc[i][3] += bb.w;
                *(float4*)&vlR[(4 * tq + i) * 68 + 4 * dq] =
                    make_float4(acc[i][0], acc[i][1], acc[i][2], acc[i][3]);
            }
#pragma unroll
            for (int j = 0; j < 4; j++) {
                float4 cv = make_float4(acc[0][j], acc[1][j], acc[2][j], acc[3][j]);
                *(float4*)&vcT[(4 * dq + j) * 20 + 4 * tq] = cv;
            }
        }
        __syncthreads();

        // ---------------- P2: logits + softmax + P@vl (all waves) ----------
        float lg = 0.f;
#pragma unroll
        for (int c = 0; c < 16; ++c) {
            float4 a4 = *(float4*)&qsR[t2 * 68 + 4 * c];
            float4 b4 = *(float4*)&ksR[u  * 68 + 4 * c];
            lg = dot4acc(a4, b4, lg);
        }
        lg *= 0.125f;                        // 1/sqrt(64)
        float mx = lg;
        for (int off = 8; off; off >>= 1) mx = fmaxf(mx, __shfl_xor(mx, off));
        float e = __expf(lg - mx);
        float sm = e;
        for (int off = 8; off; off >>= 1) sm += __shfl_xor(sm, off);
        float p = e / sm;

        float4 ai = f4zero();
        int gbase = lane & 48;
#pragma unroll
        for (int tk = 0; tk < 16; ++tk) {
            float pk = __shfl(p, gbase + tk);
            ai = f4fma(pk, *(float4*)&vlR[tk * 68 + 4 * u], ai);
        }

        if (it == 0) {
            ai0 = ai;
        } else if (it == 1) {
            dlocal = fabsf(ai.x - ai0.x) + fabsf(ai.y - ai0.y) +
                     fabsf(ai.z - ai0.z) + fabsf(ai.w - ai0.w);
            *(float4*)&ai1g[rowi2 * 1024 + col2] = ai;
        } else {
            *(float4*)&ai2g[rowi2 * 1024 + col2] = ai;
        }
        qcT[(4 * u + 0) * 20 + t2] += ai.x;
        qcT[(4 * u + 1) * 20 + t2] += ai.y;
        qcT[(4 * u + 2) * 20 + t2] += ai.z;
        qcT[(4 * u + 3) * 20 + t2] += ai.w;
        __syncthreads();
    }

    float ds = dlocal;
    for (int off = 32; off; off >>= 1) ds += __shfl_xor(ds, off);
    if (lane == 0) dred[wv] = ds;
    __syncthreads();
    if (tid == 0) atomicAdd(diffg, dred[0] + dred[1] + dred[2] + dred[3]);
}

// ---------------- K4: ai_sel @ Wo^T, split-K partials ----------------
__global__ __launch_bounds__(256) void k_wo(const float* __restrict__ ai1g,
                                            const float* __restrict__ ai2g,
                                            const float* __restrict__ diffg,
                                            const float* __restrict__ thrp,
                                            const float* __restrict__ facp,
                                            const float* __restrict__ Wo,
                                            float* __restrict__ wop) {
    float diff = diffg[0] * (1.0f / 8388608.0f);
    const float* A = (diff < thrp[0] + facp[0] * diff) ? ai1g : ai2g;
    int jt  = blockIdx.x;
    int ksl = blockIdx.y;
    int k0  = ksl * 128;
    __shared__ float At[64][132];
    __shared__ float Bt[32][132];
    int tid = threadIdx.x;
    for (int i = tid; i < 2048; i += 256) {
        int r = i >> 5, kk = (i & 31) << 2;
        *(float4*)&At[r][kk] = *(const float4*)&A[r * 1024 + k0 + kk];
    }
    for (int i = tid; i < 1024; i += 256) {
        int r = i >> 5, kk = (i & 31) << 2;
        *(float4*)&Bt[r][kk] = *(const float4*)&Wo[(size_t)(jt * 32 + r) * 1024 + k0 + kk];
    }
    __syncthreads();
    int rg = tid >> 4, cg = tid & 15;
    float acc[4][2];
#pragma unroll
    for (int i = 0; i < 4; i++) { acc[i][0] = 0.f; acc[i][1] = 0.f; }
    for (int k = 0; k < 128; k += 4) {
        float4 b0 = *(float4*)&Bt[cg * 2 + 0][k];
        float4 b1 = *(float4*)&Bt[cg * 2 + 1][k];
#pragma unroll
        for (int i = 0; i < 4; i++) {
            float4 a = *(float4*)&At[rg * 4 + i][k];
            acc[i][0] = dot4acc(a, b0, acc[i][0]);
            acc[i][1] = dot4acc(a, b1, acc[i][1]);
        }
    }
    float* dst = wop + (size_t)ksl * 65536;
    int colg = jt * 32 + cg * 2;
#pragma unroll
    for (int i = 0; i < 4; i++) {
        *(float2*)&dst[(rg * 4 + i) * 1024 + colg] = make_float2(acc[i][0], acc[i][1]);
    }
}

// ---------------- K5: final output write ----------------
__global__ __launch_bounds__(256) void k_bo(const float* __restrict__ bo,
                                            const float* __restrict__ wop,
                                            float* __restrict__ out) {
    int row = blockIdx.x;
    int tid = threadIdx.x;
    int b = row >> 11, t = row & 2047;
    float4 o = *(const float4*)&bo[tid * 4];
    if (t < 16) {
        int ri = b * 16 + t;
#pragma unroll
        for (int s = 0; s < 8; s++) {
            float4 p = *(const float4*)&wop[(size_t)s * 65536 + ri * 1024 + tid * 4];
            o = f4add(o, p);
        }
    }
    *(float4*)&out[(size_t)row * 1024 + tid * 4] = o;
}

extern "C" void kernel_launch(void* const* d_in, const int* in_sizes, int n_in,
                              void* d_out, int out_size, void* d_ws, size_t ws_size,
                              hipStream_t stream) {
    (void)in_sizes; (void)n_in; (void)out_size; (void)ws_size;
    const float* x    = (const float*)d_in[0];
    const float* Wq   = (const float*)d_in[1];
    const float* bq   = (const float*)d_in[2];
    const float* Wk   = (const float*)d_in[3];
    const float* Wv   = (const float*)d_in[4];
    const float* bv   = (const float*)d_in[5];
    const float* Wo   = (const float*)d_in[6];
    const float* bo   = (const float*)d_in[7];
    const float* lna  = (const float*)d_in[8];
    const float* lnc  = (const float*)d_in[9];
    const float* lnd  = (const float*)d_in[10];
    const float* Wlq  = (const float*)d_in[11];
    const float* blq  = (const float*)d_in[12];
    const float* Wlk  = (const float*)d_in[13];
    const float* blk_ = (const float*)d_in[14];
    const float* Wlv  = (const float*)d_in[15];
    const float* blv  = (const float*)d_in[16];
    const float* temp = (const float*)d_in[17];
    const float* thr  = (const float*)d_in[18];
    const float* fac  = (const float*)d_in[19];
    float* ws  = (float*)d_ws;
    float* out = (float*)d_out;

    k_ln  <<<67, 256, 0, stream>>>(x, lna, Wlq, Wlk, Wlv,
                                   ws + WS_XN, ws + WS_WT, ws + WS_DIFF);
    k_qkv <<<dim3(96, 8), 256, 0, stream>>>(ws + WS_XN, Wq, Wk, Wv, ws + WS_QKVP);
    k_fold<<<dim3(3, 64), 256, 0, stream>>>(ws + WS_QKVP, bq, bv, ws + WS_QF);
    k_iter<<<64, 256, 0, stream>>>(ws + WS_QF, ws + WS_WT, lnc, lnd,
                                   blq, blk_, blv, temp,
                                   ws + WS_AI1, ws + WS_AI2, ws + WS_DIFF);
    k_wo  <<<dim3(32, 8), 256, 0, stream>>>(ws + WS_AI1, ws + WS_AI2, ws + WS_DIFF,
                                            thr, fac, Wo, ws + WS_WOP);
    k_bo  <<<8192, 256, 0, stream>>>(bo, ws + WS_WOP, out);
}

// Round 6
// 166.769 us; speedup vs baseline: 1.3383x; 1.2442x over previous
//
#include <hip/hip_runtime.h>
#include <math.h>

// ---------------- workspace layout (float offsets) ----------------
// Only the first 16 tokens per batch matter (E = HEAD = 16 slices the T axis).
#define WS_XN    0          // 64*1024                  LN'd x rows
#define WS_QKVP  65536      // 8 * 64*3072              split-K partials of q|k|v
#define WS_DIFF  1638400    // 1                        sum |ai1-ai0|
#define WS_AI1   1638404    // 64*1024                  iter-1 attention out
#define WS_AI2   1703940    // 64*1024                  iter-2 attention out
#define WS_WOP   1769476    // 8 * 64*1024              split-K partials of ai_sel @ Wo^T
#define WS_WT    2293764    // 3 * 4096                 WlqT|WlkT|WlvT  ([k][d] layout)
#define WS_QF    2306052    // 64*3072                  folded q|k|v (scale/bias applied)
// end: 2502660 floats = ~10 MB

__device__ __forceinline__ float4 f4zero() { return make_float4(0.f, 0.f, 0.f, 0.f); }
__device__ __forceinline__ float4 f4add(float4 a, float4 b) {
    return make_float4(a.x + b.x, a.y + b.y, a.z + b.z, a.w + b.w);
}
__device__ __forceinline__ float4 f4fma(float s, float4 a, float4 c) {
    return make_float4(fmaf(s, a.x, c.x), fmaf(s, a.y, c.y),
                       fmaf(s, a.z, c.z), fmaf(s, a.w, c.w));
}
__device__ __forceinline__ float dot4acc(float4 a, float4 b, float acc) {
    acc = fmaf(a.x, b.x, acc); acc = fmaf(a.y, b.y, acc);
    acc = fmaf(a.z, b.z, acc); acc = fmaf(a.w, b.w, acc);
    return acc;
}

// 16x64 @ 64x64 GEMM inner loop: LDS A ([k][t] stride 20), global B ([k][d]).
// Register double-buffer of 8 float4 weight loads per batch.
// CRITICAL: kb loop must be `#pragma unroll 1` -- full unroll flattens the
// double-buffer into 64 live float4 (R4/R5 spill: 14.6 MB scratch WRITE_SIZE).
__device__ __forceinline__ void gemm_16x64(const float* __restrict__ ldsA, int tq,
                                           const float* __restrict__ WT, int dq,
                                           float acc[4][4]) {
    float4 wA[8];
#pragma unroll
    for (int j = 0; j < 8; ++j)
        wA[j] = *(const float4*)&WT[j * 64 + 4 * dq];
#pragma unroll 1
    for (int kb = 0; kb < 64; kb += 8) {
        float4 wB[8];
        if (kb + 8 < 64) {
#pragma unroll
            for (int j = 0; j < 8; ++j)
                wB[j] = *(const float4*)&WT[(kb + 8 + j) * 64 + 4 * dq];
        }
#pragma unroll
        for (int j = 0; j < 8; ++j) {
            float4 a4 = *(const float4*)&ldsA[(kb + j) * 20 + 4 * tq];
            float4 b4 = wA[j];
            float av[4] = { a4.x, a4.y, a4.z, a4.w };
#pragma unroll
            for (int i = 0; i < 4; i++) {
                acc[i][0] = fmaf(av[i], b4.x, acc[i][0]);
                acc[i][1] = fmaf(av[i], b4.y, acc[i][1]);
                acc[i][2] = fmaf(av[i], b4.z, acc[i][2]);
                acc[i][3] = fmaf(av[i], b4.w, acc[i][3]);
            }
        }
        if (kb + 8 < 64) {
#pragma unroll
            for (int j = 0; j < 8; ++j) wA[j] = wB[j];
        }
    }
}

// ---------------- K1: LayerNorm of 64 rows + weight transpose ----------------
__global__ __launch_bounds__(256) void k_ln(const float* __restrict__ x,
                                            const float* __restrict__ lna,
                                            const float* __restrict__ Wlq,
                                            const float* __restrict__ Wlk,
                                            const float* __restrict__ Wlv,
                                            float* __restrict__ xn,
                                            float* __restrict__ wt,
                                            float* __restrict__ diffg) {
    if (blockIdx.x >= 64) {
        int m = blockIdx.x - 64;
        const float* W = (m == 0) ? Wlq : (m == 1) ? Wlk : Wlv;
        float* dst = wt + m * 4096;
        for (int i = threadIdx.x; i < 4096; i += 256) {
            int k = i >> 6, d = i & 63;
            dst[i] = W[d * 64 + k];
        }
        return;
    }
    int r = blockIdx.x;                 // 0..63 = b*16 + t
    int b = r >> 4, t = r & 15;
    if (blockIdx.x == 0 && threadIdx.x == 0) diffg[0] = 0.f;
    const float* row = x + (size_t)(b * 2048 + t) * 1024;
    int tid = threadIdx.x;
    float4 xv = *(const float4*)&row[tid * 4];
    float s1 = xv.x + xv.y + xv.z + xv.w;
    float s2 = xv.x * xv.x + xv.y * xv.y + xv.z * xv.z + xv.w * xv.w;
    for (int off = 32; off; off >>= 1) {
        s1 += __shfl_xor(s1, off);
        s2 += __shfl_xor(s2, off);
    }
    __shared__ float ssum[4], ssq[4];
    int wv = tid >> 6, lane = tid & 63;
    if (lane == 0) { ssum[wv] = s1; ssq[wv] = s2; }
    __syncthreads();
    float tot = ssum[0] + ssum[1] + ssum[2] + ssum[3];
    float tq  = ssq[0] + ssq[1] + ssq[2] + ssq[3];
    float m   = tot * (1.0f / 1024.0f);
    float var = tq * (1.0f / 1024.0f) - m * m;
    float rs  = rsqrtf(var + 1e-5f);
    float4 w4 = *(const float4*)&lna[tid * 4];
    float4 o  = make_float4((xv.x - m) * rs * w4.x, (xv.y - m) * rs * w4.y,
                            (xv.z - m) * rs * w4.z, (xv.w - m) * rs * w4.w);
    *(float4*)&xn[r * 1024 + tid * 4] = o;
}

// ---------------- K2: q|k|v = xn @ [Wq|Wk|Wv]^T, split-K partials ----------------
__global__ __launch_bounds__(256) void k_qkv(const float* __restrict__ xn,
                                             const float* __restrict__ Wq,
                                             const float* __restrict__ Wk,
                                             const float* __restrict__ Wv,
                                             float* __restrict__ qkvp) {
    int ct  = blockIdx.x;               // 0..95
    int ksl = blockIdx.y;               // 0..7
    int m   = ct >> 5;
    const float* W = (m == 0) ? Wq : (m == 1) ? Wk : Wv;
    int j0 = (ct & 31) * 32;
    int k0 = ksl * 128;
    __shared__ float At[64][132];
    __shared__ float Bt[32][132];
    int tid = threadIdx.x;
    for (int i = tid; i < 2048; i += 256) {
        int r = i >> 5, kk = (i & 31) << 2;
        *(float4*)&At[r][kk] = *(const float4*)&xn[r * 1024 + k0 + kk];
    }
    for (int i = tid; i < 1024; i += 256) {
        int r = i >> 5, kk = (i & 31) << 2;
        *(float4*)&Bt[r][kk] = *(const float4*)&W[(size_t)(j0 + r) * 1024 + k0 + kk];
    }
    __syncthreads();
    int rg = tid >> 4, cg = tid & 15;
    float acc[4][2];
#pragma unroll
    for (int i = 0; i < 4; i++) { acc[i][0] = 0.f; acc[i][1] = 0.f; }
    for (int k = 0; k < 128; k += 4) {
        float4 b0 = *(float4*)&Bt[cg * 2 + 0][k];
        float4 b1 = *(float4*)&Bt[cg * 2 + 1][k];
#pragma unroll
        for (int i = 0; i < 4; i++) {
            float4 a = *(float4*)&At[rg * 4 + i][k];
            acc[i][0] = dot4acc(a, b0, acc[i][0]);
            acc[i][1] = dot4acc(a, b1, acc[i][1]);
        }
    }
    float* dst = qkvp + (size_t)ksl * 196608;
    int colg = ct * 32 + cg * 2;
#pragma unroll
    for (int i = 0; i < 4; i++) {
        *(float2*)&dst[(rg * 4 + i) * 3072 + colg] = make_float2(acc[i][0], acc[i][1]);
    }
}

// ---------------- K2b: fold split-K partials, apply scale/bias ----------------
__global__ __launch_bounds__(256) void k_fold(const float* __restrict__ qkvp,
                                              const float* __restrict__ bq,
                                              const float* __restrict__ bv,
                                              float* __restrict__ qf) {
    int m   = blockIdx.x;               // 0=q, 1=k, 2=v
    int row = blockIdx.y;
    int cc  = threadIdx.x * 4;
    int col = m * 1024 + cc;
    float4 s = f4zero();
#pragma unroll
    for (int sl = 0; sl < 8; sl++)
        s = f4add(s, *(const float4*)&qkvp[(size_t)sl * 196608 + row * 3072 + col]);
    const float SCALE = 0.35355339059327378f;   // 64^-0.25
    if (m == 0) {
        float4 b = *(const float4*)&bq[cc];
        s = make_float4((s.x + b.x) * SCALE, (s.y + b.y) * SCALE,
                        (s.z + b.z) * SCALE, (s.w + b.w) * SCALE);
    } else if (m == 1) {
        s = make_float4(s.x * SCALE, s.y * SCALE, s.z * SCALE, s.w * SCALE);
    } else {
        float4 b = *(const float4*)&bv[cc];
        s = f4add(s, b);
    }
    *(float4*)&qf[row * 3072 + col] = s;
}

// ---------------- K3: 3-iteration loop, one block per (b,h) ----------------
// Weights streamed from global wt (L1/L2-hot) with register double-buffered
// 8-wide batches (gemm_16x64, kb loop NOT unrolled). launch_bounds(256,1):
// grid is 64 blocks on 256 CUs so occupancy is 1 block/CU regardless; give
// the allocator full VGPR headroom to avoid any spill.
__global__ __launch_bounds__(256, 1) void k_iter(
        const float* __restrict__ qf, const float* __restrict__ wt,
        const float* __restrict__ lnc, const float* __restrict__ lnd,
        const float* __restrict__ blq, const float* __restrict__ blk_,
        const float* __restrict__ blv, const float* __restrict__ temp,
        float* __restrict__ ai1g, float* __restrict__ ai2g,
        float* __restrict__ diffg) {
    __shared__ __align__(16) float qcT[64 * 20];   // [d-or-k][t] stride 20
    __shared__ __align__(16) float kcT[64 * 20];
    __shared__ __align__(16) float vcT[64 * 20];
    __shared__ __align__(16) float qsR[16 * 68];   // row-major [t][d]
    __shared__ __align__(16) float ksR[16 * 68];
    __shared__ __align__(16) float vlR[16 * 68];
    __shared__ float dred[4];

    int tid  = threadIdx.x;
    int b    = blockIdx.x >> 4, h = blockIdx.x & 15;
    int wv   = tid >> 6, lane = tid & 63;
    float tempv = temp[0];

    int tq = lane >> 4, dq = lane & 15;     // P1 tile coords
    int t2 = tid >> 4,  u  = tid & 15;      // P2 coords
    int rowi2 = b * 16 + t2, col2 = h * 64 + u * 4;

    // ---- staging loads (3 float4 per thread)
    const float* R = qf + rowi2 * 3072 + h * 64 + u * 4;
    float4 q4 = *(const float4*)&R[0];
    float4 k4 = *(const float4*)&R[1024];
    float4 v4 = *(const float4*)&R[2048];
    {
        float qv[4] = { q4.x, q4.y, q4.z, q4.w };
        float kv[4] = { k4.x, k4.y, k4.z, k4.w };
        float vv[4] = { v4.x, v4.y, v4.z, v4.w };
#pragma unroll
        for (int c = 0; c < 4; c++) {
            qcT[(u * 4 + c) * 20 + t2] = qv[c];
            kcT[(u * 4 + c) * 20 + t2] = kv[c];
            vcT[(u * 4 + c) * 20 + t2] = vv[c];
        }
    }
    __syncthreads();

    float4 ai0 = f4zero();
    float  dlocal = 0.f;

#pragma unroll 1
    for (int it = 0; it < 3; ++it) {
        float t_it = tempv + 0.005f * (float)it;
        float tsc  = (t_it != 1.0f && t_it > 0.0f) ? rsqrtf(t_it) : 1.0f;

        // ---------------- P1: three GEMMs, wave-specialized ----------------
        if (wv == 0) {
            float acc[4][4];
#pragma unroll
            for (int i = 0; i < 4; i++)
#pragma unroll
                for (int j = 0; j < 4; j++) acc[i][j] = 0.f;
            gemm_16x64(qcT, tq, wt, dq, acc);
            float4 bb = *(const float4*)&blq[4 * dq];
            float4 lw = *(const float4*)&lnc[4 * dq];
#pragma unroll
            for (int i = 0; i < 4; i++) {
                acc[i][0] += bb.x; acc[i][1] += bb.y;
                acc[i][2] += bb.z; acc[i][3] += bb.w;
                float s1 = acc[i][0] + acc[i][1] + acc[i][2] + acc[i][3];
                float s2 = acc[i][0]*acc[i][0] + acc[i][1]*acc[i][1]
                         + acc[i][2]*acc[i][2] + acc[i][3]*acc[i][3];
                for (int off = 8; off; off >>= 1) {
                    s1 += __shfl_xor(s1, off); s2 += __shfl_xor(s2, off);
                }
                float m  = s1 * (1.0f / 64.0f);
                float vr = s2 * (1.0f / 64.0f) - m * m;
                float rs = rsqrtf(vr + 1e-5f) * tsc;
                float4 o = make_float4((acc[i][0] - m) * rs * lw.x,
                                       (acc[i][1] - m) * rs * lw.y,
                                       (acc[i][2] - m) * rs * lw.z,
                                       (acc[i][3] - m) * rs * lw.w);
                *(float4*)&qsR[(4 * tq + i) * 68 + 4 * dq] = o;
            }
        } else if (wv == 1) {
            float acc[4][4];
#pragma unroll
            for (int i = 0; i < 4; i++)
#pragma unroll
                for (int j = 0; j < 4; j++) acc[i][j] = 0.f;
            gemm_16x64(kcT, tq, wt + 4096, dq, acc);
            float4 bb = *(const float4*)&blk_[4 * dq];
#pragma unroll
            for (int i = 0; i < 4; i++) {
                acc[i][0] += bb.x; acc[i][1] += bb.y;
                acc[i][2] += bb.z; acc[i][3] += bb.w;
            }
#pragma unroll
            for (int j = 0; j < 4; j++) {
                float4 cv = make_float4(acc[0][j], acc[1][j], acc[2][j], acc[3][j]);
                *(float4*)&kcT[(4 * dq + j) * 20 + 4 * tq] = cv;
            }
            float4 lw = *(const float4*)&lnd[4 * dq];
#pragma unroll
            for (int i = 0; i < 4; i++) {
                float s1 = acc[i][0] + acc[i][1] + acc[i][2] + acc[i][3];
                float s2 = acc[i][0]*acc[i][0] + acc[i][1]*acc[i][1]
                         + acc[i][2]*acc[i][2] + acc[i][3]*acc[i][3];
                for (int off = 8; off; off >>= 1) {
                    s1 += __shfl_xor(s1, off); s2 += __shfl_xor(s2, off);
                }
                float m  = s1 * (1.0f / 64.0f);
                float vr = s2 * (1.0f / 64.0f) - m * m;
                float rs = rsqrtf(vr + 1e-5f);
                float4 o = make_float4((acc[i][0] - m) * rs * lw.x,
                                       (acc[i][1] - m) * rs * lw.y,
                                       (acc[i][2] - m) * rs * lw.z,
                                       (acc[i][3] - m) * rs * lw.w);
                *(float4*)&ksR[(4 * tq + i) * 68 + 4 * dq] = o;
            }
        } else if (wv == 2) {
            float acc[4][4];
#pragma unroll
            for (int i = 0; i < 4; i++)
#pragma unroll
                for (int j = 0; j < 4; j++) acc[i][j] = 0.f;
            gemm_16x64(vcT, tq, wt + 8192, dq, acc);
            float4 bb = *(const float4*)&blv[4 * dq];
#pragma unroll
            for (int i = 0; i < 4; i++) {
                acc[i][0] += bb.x; acc[i][1] += bb.y;
                acc[i][2] += bb.z; acc[i][3] += bb.w;
                *(float4*)&vlR[(4 * tq + i) * 68 + 4 * dq] =
                    make_float4(acc[i][0], acc[i][1], acc[i][2], acc[i][3]);
            }
#pragma unroll
            for (int j = 0; j < 4; j++) {
                float4 cv = make_float4(acc[0][j], acc[1][j], acc[2][j], acc[3][j]);
                *(float4*)&vcT[(4 * dq + j) * 20 + 4 * tq] = cv;
            }
        }
        __syncthreads();

        // ---------------- P2: logits + softmax + P@vl (all waves) ----------
        float lg = 0.f;
#pragma unroll
        for (int c = 0; c < 16; ++c) {
            float4 a4 = *(float4*)&qsR[t2 * 68 + 4 * c];
            float4 b4 = *(float4*)&ksR[u  * 68 + 4 * c];
            lg = dot4acc(a4, b4, lg);
        }
        lg *= 0.125f;                        // 1/sqrt(64)
        float mx = lg;
        for (int off = 8; off; off >>= 1) mx = fmaxf(mx, __shfl_xor(mx, off));
        float e = __expf(lg - mx);
        float sm = e;
        for (int off = 8; off; off >>= 1) sm += __shfl_xor(sm, off);
        float p = e / sm;

        float4 ai = f4zero();
        int gbase = lane & 48;
#pragma unroll
        for (int tk = 0; tk < 16; ++tk) {
            float pk = __shfl(p, gbase + tk);
            ai = f4fma(pk, *(float4*)&vlR[tk * 68 + 4 * u], ai);
        }

        if (it == 0) {
            ai0 = ai;
        } else if (it == 1) {
            dlocal = fabsf(ai.x - ai0.x) + fabsf(ai.y - ai0.y) +
                     fabsf(ai.z - ai0.z) + fabsf(ai.w - ai0.w);
            *(float4*)&ai1g[rowi2 * 1024 + col2] = ai;
        } else {
            *(float4*)&ai2g[rowi2 * 1024 + col2] = ai;
        }
        qcT[(4 * u + 0) * 20 + t2] += ai.x;
        qcT[(4 * u + 1) * 20 + t2] += ai.y;
        qcT[(4 * u + 2) * 20 + t2] += ai.z;
        qcT[(4 * u + 3) * 20 + t2] += ai.w;
        __syncthreads();
    }

    float ds = dlocal;
    for (int off = 32; off; off >>= 1) ds += __shfl_xor(ds, off);
    if (lane == 0) dred[wv] = ds;
    __syncthreads();
    if (tid == 0) atomicAdd(diffg, dred[0] + dred[1] + dred[2] + dred[3]);
}

// ---------------- K4: ai_sel @ Wo^T, split-K partials ----------------
__global__ __launch_bounds__(256) void k_wo(const float* __restrict__ ai1g,
                                            const float* __restrict__ ai2g,
                                            const float* __restrict__ diffg,
                                            const float* __restrict__ thrp,
                                            const float* __restrict__ facp,
                                            const float* __restrict__ Wo,
                                            float* __restrict__ wop) {
    float diff = diffg[0] * (1.0f / 8388608.0f);
    const float* A = (diff < thrp[0] + facp[0] * diff) ? ai1g : ai2g;
    int jt  = blockIdx.x;
    int ksl = blockIdx.y;
    int k0  = ksl * 128;
    __shared__ float At[64][132];
    __shared__ float Bt[32][132];
    int tid = threadIdx.x;
    for (int i = tid; i < 2048; i += 256) {
        int r = i >> 5, kk = (i & 31) << 2;
        *(float4*)&At[r][kk] = *(const float4*)&A[r * 1024 + k0 + kk];
    }
    for (int i = tid; i < 1024; i += 256) {
        int r = i >> 5, kk = (i & 31) << 2;
        *(float4*)&Bt[r][kk] = *(const float4*)&Wo[(size_t)(jt * 32 + r) * 1024 + k0 + kk];
    }
    __syncthreads();
    int rg = tid >> 4, cg = tid & 15;
    float acc[4][2];
#pragma unroll
    for (int i = 0; i < 4; i++) { acc[i][0] = 0.f; acc[i][1] = 0.f; }
    for (int k = 0; k < 128; k += 4) {
        float4 b0 = *(float4*)&Bt[cg * 2 + 0][k];
        float4 b1 = *(float4*)&Bt[cg * 2 + 1][k];
#pragma unroll
        for (int i = 0; i < 4; i++) {
            float4 a = *(float4*)&At[rg * 4 + i][k];
            acc[i][0] = dot4acc(a, b0, acc[i][0]);
            acc[i][1] = dot4acc(a, b1, acc[i][1]);
        }
    }
    float* dst = wop + (size_t)ksl * 65536;
    int colg = jt * 32 + cg * 2;
#pragma unroll
    for (int i = 0; i < 4; i++) {
        *(float2*)&dst[(rg * 4 + i) * 1024 + colg] = make_float2(acc[i][0], acc[i][1]);
    }
}

// ---------------- K5: final output write ----------------
__global__ __launch_bounds__(256) void k_bo(const float* __restrict__ bo,
                                            const float* __restrict__ wop,
                                            float* __restrict__ out) {
    int row = blockIdx.x;
    int tid = threadIdx.x;
    int b = row >> 11, t = row & 2047;
    float4 o = *(const float4*)&bo[tid * 4];
    if (t < 16) {
        int ri = b * 16 + t;
#pragma unroll
        for (int s = 0; s < 8; s++) {
            float4 p = *(const float4*)&wop[(size_t)s * 65536 + ri * 1024 + tid * 4];
            o = f4add(o, p);
        }
    }
    *(float4*)&out[(size_t)row * 1024 + tid * 4] = o;
}

extern "C" void kernel_launch(void* const* d_in, const int* in_sizes, int n_in,
                              void* d_out, int out_size, void* d_ws, size_t ws_size,
                              hipStream_t stream) {
    (void)in_sizes; (void)n_in; (void)out_size; (void)ws_size;
    const float* x    = (const float*)d_in[0];
    const float* Wq   = (const float*)d_in[1];
    const float* bq   = (const float*)d_in[2];
    const float* Wk   = (const float*)d_in[3];
    const float* Wv   = (const float*)d_in[4];
    const float* bv   = (const float*)d_in[5];
    const float* Wo   = (const float*)d_in[6];
    const float* bo   = (const float*)d_in[7];
    const float* lna  = (const float*)d_in[8];
    const float* lnc  = (const float*)d_in[9];
    const float* lnd  = (const float*)d_in[10];
    const float* Wlq  = (const float*)d_in[11];
    const float* blq  = (const float*)d_in[12];
    const float* Wlk  = (const float*)d_in[13];
    const float* blk_ = (const float*)d_in[14];
    const float* Wlv  = (const float*)d_in[15];
    const float* blv  = (const float*)d_in[16];
    const float* temp = (const float*)d_in[17];
    const float* thr  = (const float*)d_in[18];
    const float* fac  = (const float*)d_in[19];
    float* ws  = (float*)d_ws;
    float* out = (float*)d_out;

    k_ln  <<<67, 256, 0, stream>>>(x, lna, Wlq, Wlk, Wlv,
                                   ws + WS_XN, ws + WS_WT, ws + WS_DIFF);
    k_qkv <<<dim3(96, 8), 256, 0, stream>>>(ws + WS_XN, Wq, Wk, Wv, ws + WS_QKVP);
    k_fold<<<dim3(3, 64), 256, 0, stream>>>(ws + WS_QKVP, bq, bv, ws + WS_QF);
    k_iter<<<64, 256, 0, stream>>>(ws + WS_QF, ws + WS_WT, lnc, lnd,
                                   blq, blk_, blv, temp,
                                   ws + WS_AI1, ws + WS_AI2, ws + WS_DIFF);
    k_wo  <<<dim3(32, 8), 256, 0, stream>>>(ws + WS_AI1, ws + WS_AI2, ws + WS_DIFF,
                                            thr, fac, Wo, ws + WS_WOP);
    k_bo  <<<8192, 256, 0, stream>>>(bo, ws + WS_WOP, out);
}

// Round 7
// 160.243 us; speedup vs baseline: 1.3928x; 1.0407x over previous
//
#include <hip/hip_runtime.h>
#include <math.h>

// ---------------- workspace layout (float offsets) ----------------
// Only the first 16 tokens per batch matter (E = HEAD = 16 slices the T axis).
#define WS_XN    0          // 64*1024                  LN'd x rows
#define WS_QKVP  65536      // 8 * 64*3072              split-K partials of q|k|v
#define WS_DIFF  1638400    // 1                        sum |ai1-ai0|
#define WS_AI1   1638404    // 64*1024                  iter-1 attention out
#define WS_AI2   1703940    // 64*1024                  iter-2 attention out
#define WS_WOP   1769476    // 8 * 64*1024              split-K partials of ai_sel @ Wo^T
#define WS_WT    2293764    // 3 * 4096                 WlqT|WlkT|WlvT  ([k][d] layout)
// end: 2306052 floats = ~9.2 MB

__device__ __forceinline__ float4 f4zero() { return make_float4(0.f, 0.f, 0.f, 0.f); }
__device__ __forceinline__ float4 f4add(float4 a, float4 b) {
    return make_float4(a.x + b.x, a.y + b.y, a.z + b.z, a.w + b.w);
}
__device__ __forceinline__ float4 f4fma(float s, float4 a, float4 c) {
    return make_float4(fmaf(s, a.x, c.x), fmaf(s, a.y, c.y),
                       fmaf(s, a.z, c.z), fmaf(s, a.w, c.w));
}
__device__ __forceinline__ float dot4acc(float4 a, float4 b, float acc) {
    acc = fmaf(a.x, b.x, acc); acc = fmaf(a.y, b.y, acc);
    acc = fmaf(a.z, b.z, acc); acc = fmaf(a.w, b.w, acc);
    return acc;
}

// 16x64 @ 64x64 GEMM, both operands in LDS. A: [k][t] stride 20 (broadcast
// reads). W: [k][d] stride 64 (16 distinct float4/wave -> 2-way banks, free).
// unroll 8 keeps ~16 ds_reads outstanding; VALU-bound at 16 FMA/k-step.
__device__ __forceinline__ void gemm_lds(const float* __restrict__ ldsA, int tq,
                                         const float* __restrict__ ldsW, int dq,
                                         float acc[4][4]) {
#pragma unroll 8
    for (int k = 0; k < 64; ++k) {
        float4 a4 = *(const float4*)&ldsA[k * 20 + 4 * tq];
        float4 b4 = *(const float4*)&ldsW[k * 64 + 4 * dq];
        float av[4] = { a4.x, a4.y, a4.z, a4.w };
#pragma unroll
        for (int i = 0; i < 4; i++) {
            acc[i][0] = fmaf(av[i], b4.x, acc[i][0]);
            acc[i][1] = fmaf(av[i], b4.y, acc[i][1]);
            acc[i][2] = fmaf(av[i], b4.z, acc[i][2]);
            acc[i][3] = fmaf(av[i], b4.w, acc[i][3]);
        }
    }
}

// ---------------- K1: LayerNorm of 64 rows + weight transpose ----------------
__global__ __launch_bounds__(256) void k_ln(const float* __restrict__ x,
                                            const float* __restrict__ lna,
                                            const float* __restrict__ Wlq,
                                            const float* __restrict__ Wlk,
                                            const float* __restrict__ Wlv,
                                            float* __restrict__ xn,
                                            float* __restrict__ wt,
                                            float* __restrict__ diffg) {
    if (blockIdx.x >= 64) {
        int m = blockIdx.x - 64;
        const float* W = (m == 0) ? Wlq : (m == 1) ? Wlk : Wlv;
        float* dst = wt + m * 4096;
        for (int i = threadIdx.x; i < 4096; i += 256) {
            int k = i >> 6, d = i & 63;
            dst[i] = W[d * 64 + k];
        }
        return;
    }
    int r = blockIdx.x;                 // 0..63 = b*16 + t
    int b = r >> 4, t = r & 15;
    if (blockIdx.x == 0 && threadIdx.x == 0) diffg[0] = 0.f;
    const float* row = x + (size_t)(b * 2048 + t) * 1024;
    int tid = threadIdx.x;
    float4 xv = *(const float4*)&row[tid * 4];
    float s1 = xv.x + xv.y + xv.z + xv.w;
    float s2 = xv.x * xv.x + xv.y * xv.y + xv.z * xv.z + xv.w * xv.w;
    for (int off = 32; off; off >>= 1) {
        s1 += __shfl_xor(s1, off);
        s2 += __shfl_xor(s2, off);
    }
    __shared__ float ssum[4], ssq[4];
    int wv = tid >> 6, lane = tid & 63;
    if (lane == 0) { ssum[wv] = s1; ssq[wv] = s2; }
    __syncthreads();
    float tot = ssum[0] + ssum[1] + ssum[2] + ssum[3];
    float tq  = ssq[0] + ssq[1] + ssq[2] + ssq[3];
    float m   = tot * (1.0f / 1024.0f);
    float var = tq * (1.0f / 1024.0f) - m * m;
    float rs  = rsqrtf(var + 1e-5f);
    float4 w4 = *(const float4*)&lna[tid * 4];
    float4 o  = make_float4((xv.x - m) * rs * w4.x, (xv.y - m) * rs * w4.y,
                            (xv.z - m) * rs * w4.z, (xv.w - m) * rs * w4.w);
    *(float4*)&xn[r * 1024 + tid * 4] = o;
}

// ---------------- K2: q|k|v = xn @ [Wq|Wk|Wv]^T, split-K partials ----------------
__global__ __launch_bounds__(256) void k_qkv(const float* __restrict__ xn,
                                             const float* __restrict__ Wq,
                                             const float* __restrict__ Wk,
                                             const float* __restrict__ Wv,
                                             float* __restrict__ qkvp) {
    int ct  = blockIdx.x;               // 0..95
    int ksl = blockIdx.y;               // 0..7
    int m   = ct >> 5;
    const float* W = (m == 0) ? Wq : (m == 1) ? Wk : Wv;
    int j0 = (ct & 31) * 32;
    int k0 = ksl * 128;
    __shared__ float At[64][132];
    __shared__ float Bt[32][132];
    int tid = threadIdx.x;
    for (int i = tid; i < 2048; i += 256) {
        int r = i >> 5, kk = (i & 31) << 2;
        *(float4*)&At[r][kk] = *(const float4*)&xn[r * 1024 + k0 + kk];
    }
    for (int i = tid; i < 1024; i += 256) {
        int r = i >> 5, kk = (i & 31) << 2;
        *(float4*)&Bt[r][kk] = *(const float4*)&W[(size_t)(j0 + r) * 1024 + k0 + kk];
    }
    __syncthreads();
    int rg = tid >> 4, cg = tid & 15;
    float acc[4][2];
#pragma unroll
    for (int i = 0; i < 4; i++) { acc[i][0] = 0.f; acc[i][1] = 0.f; }
    for (int k = 0; k < 128; k += 4) {
        float4 b0 = *(float4*)&Bt[cg * 2 + 0][k];
        float4 b1 = *(float4*)&Bt[cg * 2 + 1][k];
#pragma unroll
        for (int i = 0; i < 4; i++) {
            float4 a = *(float4*)&At[rg * 4 + i][k];
            acc[i][0] = dot4acc(a, b0, acc[i][0]);
            acc[i][1] = dot4acc(a, b1, acc[i][1]);
        }
    }
    float* dst = qkvp + (size_t)ksl * 196608;
    int colg = ct * 32 + cg * 2;
#pragma unroll
    for (int i = 0; i < 4; i++) {
        *(float2*)&dst[(rg * 4 + i) * 3072 + colg] = make_float2(acc[i][0], acc[i][1]);
    }
}

// ---------------- K3: fold + 3-iteration loop, one block per (b,h) ----------------
// All weights staged to LDS once (48 KB); split-K fold fused into staging
// (24 pipelined float4 loads/thread -- R2 showed this costs ~1 us, not 40).
// LDS total ~76 KB -> 1 block/CU (grid is 64 on 256 CUs anyway).
__global__ __launch_bounds__(256, 1) void k_iter(
        const float* __restrict__ qkvp, const float* __restrict__ wt,
        const float* __restrict__ bq,  const float* __restrict__ bv,
        const float* __restrict__ lnc, const float* __restrict__ lnd,
        const float* __restrict__ blq, const float* __restrict__ blk_,
        const float* __restrict__ blv, const float* __restrict__ temp,
        float* __restrict__ ai1g, float* __restrict__ ai2g,
        float* __restrict__ diffg) {
    __shared__ __align__(16) float wS[12288];      // WlqT|WlkT|WlvT ([k][d])
    __shared__ __align__(16) float qcT[64 * 20];   // [d-or-k][t] stride 20
    __shared__ __align__(16) float kcT[64 * 20];
    __shared__ __align__(16) float vcT[64 * 20];
    __shared__ __align__(16) float qsR[16 * 68];   // row-major [t][d]
    __shared__ __align__(16) float ksR[16 * 68];
    __shared__ __align__(16) float vlR[16 * 68];
    __shared__ float dred[4];

    int tid  = threadIdx.x;
    int b    = blockIdx.x >> 4, h = blockIdx.x & 15;
    int wv   = tid >> 6, lane = tid & 63;
    float tempv = temp[0];

    int tq = lane >> 4, dq = lane & 15;     // P1 tile coords
    int t2 = tid >> 4,  u  = tid & 15;      // P2 coords
    int rowi2 = b * 16 + t2, col2 = h * 64 + u * 4;

    // ---- weight staging: 12 float4 per thread, independent, pipelined
#pragma unroll
    for (int j = 0; j < 12; ++j) {
        int idx = (tid + j * 256) * 4;
        *(float4*)&wS[idx] = *(const float4*)&wt[idx];
    }

    // ---- fused split-K fold + scale/bias + transposed state staging
    {
        const float SCALE = 0.35355339059327378f;   // 64^-0.25
        const float* P = qkvp + rowi2 * 3072 + col2;
        float4 q4 = f4zero(), k4 = f4zero(), v4 = f4zero();
#pragma unroll
        for (int sl = 0; sl < 8; sl++) {
            const float* Ps = P + (size_t)sl * 196608;
            q4 = f4add(q4, *(const float4*)&Ps[0]);
            k4 = f4add(k4, *(const float4*)&Ps[1024]);
            v4 = f4add(v4, *(const float4*)&Ps[2048]);
        }
        float4 bq4 = *(const float4*)&bq[col2];
        float4 bv4 = *(const float4*)&bv[col2];
        float qv[4] = { (q4.x + bq4.x) * SCALE, (q4.y + bq4.y) * SCALE,
                        (q4.z + bq4.z) * SCALE, (q4.w + bq4.w) * SCALE };
        float kv[4] = { k4.x * SCALE, k4.y * SCALE, k4.z * SCALE, k4.w * SCALE };
        float vv[4] = { v4.x + bv4.x, v4.y + bv4.y, v4.z + bv4.z, v4.w + bv4.w };
#pragma unroll
        for (int c = 0; c < 4; c++) {
            qcT[(u * 4 + c) * 20 + t2] = qv[c];
            kcT[(u * 4 + c) * 20 + t2] = kv[c];
            vcT[(u * 4 + c) * 20 + t2] = vv[c];
        }
    }
    __syncthreads();

    float4 ai0 = f4zero();
    float  dlocal = 0.f;

#pragma unroll 1
    for (int it = 0; it < 3; ++it) {
        float t_it = tempv + 0.005f * (float)it;
        float tsc  = (t_it != 1.0f && t_it > 0.0f) ? rsqrtf(t_it) : 1.0f;

        // ---------------- P1: three GEMMs, wave-specialized ----------------
        if (wv == 0) {
            float acc[4][4];
#pragma unroll
            for (int i = 0; i < 4; i++)
#pragma unroll
                for (int j = 0; j < 4; j++) acc[i][j] = 0.f;
            gemm_lds(qcT, tq, wS, dq, acc);
            float4 bb = *(const float4*)&blq[4 * dq];
            float4 lw = *(const float4*)&lnc[4 * dq];
#pragma unroll
            for (int i = 0; i < 4; i++) {
                acc[i][0] += bb.x; acc[i][1] += bb.y;
                acc[i][2] += bb.z; acc[i][3] += bb.w;
                float s1 = acc[i][0] + acc[i][1] + acc[i][2] + acc[i][3];
                float s2 = acc[i][0]*acc[i][0] + acc[i][1]*acc[i][1]
                         + acc[i][2]*acc[i][2] + acc[i][3]*acc[i][3];
                for (int off = 8; off; off >>= 1) {
                    s1 += __shfl_xor(s1, off); s2 += __shfl_xor(s2, off);
                }
                float m  = s1 * (1.0f / 64.0f);
                float vr = s2 * (1.0f / 64.0f) - m * m;
                float rs = rsqrtf(vr + 1e-5f) * tsc;
                float4 o = make_float4((acc[i][0] - m) * rs * lw.x,
                                       (acc[i][1] - m) * rs * lw.y,
                                       (acc[i][2] - m) * rs * lw.z,
                                       (acc[i][3] - m) * rs * lw.w);
                *(float4*)&qsR[(4 * tq + i) * 68 + 4 * dq] = o;
            }
        } else if (wv == 1) {
            float acc[4][4];
#pragma unroll
            for (int i = 0; i < 4; i++)
#pragma unroll
                for (int j = 0; j < 4; j++) acc[i][j] = 0.f;
            gemm_lds(kcT, tq, wS + 4096, dq, acc);
            float4 bb = *(const float4*)&blk_[4 * dq];
#pragma unroll
            for (int i = 0; i < 4; i++) {
                acc[i][0] += bb.x; acc[i][1] += bb.y;
                acc[i][2] += bb.z; acc[i][3] += bb.w;
            }
#pragma unroll
            for (int j = 0; j < 4; j++) {
                float4 cv = make_float4(acc[0][j], acc[1][j], acc[2][j], acc[3][j]);
                *(float4*)&kcT[(4 * dq + j) * 20 + 4 * tq] = cv;
            }
            float4 lw = *(const float4*)&lnd[4 * dq];
#pragma unroll
            for (int i = 0; i < 4; i++) {
                float s1 = acc[i][0] + acc[i][1] + acc[i][2] + acc[i][3];
                float s2 = acc[i][0]*acc[i][0] + acc[i][1]*acc[i][1]
                         + acc[i][2]*acc[i][2] + acc[i][3]*acc[i][3];
                for (int off = 8; off; off >>= 1) {
                    s1 += __shfl_xor(s1, off); s2 += __shfl_xor(s2, off);
                }
                float m  = s1 * (1.0f / 64.0f);
                float vr = s2 * (1.0f / 64.0f) - m * m;
                float rs = rsqrtf(vr + 1e-5f);
                float4 o = make_float4((acc[i][0] - m) * rs * lw.x,
                                       (acc[i][1] - m) * rs * lw.y,
                                       (acc[i][2] - m) * rs * lw.z,
                                       (acc[i][3] - m) * rs * lw.w);
                *(float4*)&ksR[(4 * tq + i) * 68 + 4 * dq] = o;
            }
        } else if (wv == 2) {
            float acc[4][4];
#pragma unroll
            for (int i = 0; i < 4; i++)
#pragma unroll
                for (int j = 0; j < 4; j++) acc[i][j] = 0.f;
            gemm_lds(vcT, tq, wS + 8192, dq, acc);
            float4 bb = *(const float4*)&blv[4 * dq];
#pragma unroll
            for (int i = 0; i < 4; i++) {
                acc[i][0] += bb.x; acc[i][1] += bb.y;
                acc[i][2] += bb.z; acc[i][3] += bb.w;
                *(float4*)&vlR[(4 * tq + i) * 68 + 4 * dq] =
                    make_float4(acc[i][0], acc[i][1], acc[i][2], acc[i][3]);
            }
#pragma unroll
            for (int j = 0; j < 4; j++) {
                float4 cv = make_float4(acc[0][j], acc[1][j], acc[2][j], acc[3][j]);
                *(float4*)&vcT[(4 * dq + j) * 20 + 4 * tq] = cv;
            }
        }
        __syncthreads();

        // ---------------- P2: logits + softmax + P@vl (all waves) ----------
        float lg = 0.f;
#pragma unroll
        for (int c = 0; c < 16; ++c) {
            float4 a4 = *(float4*)&qsR[t2 * 68 + 4 * c];
            float4 b4 = *(float4*)&ksR[u  * 68 + 4 * c];
            lg = dot4acc(a4, b4, lg);
        }
        lg *= 0.125f;                        // 1/sqrt(64)
        float mx = lg;
        for (int off = 8; off; off >>= 1) mx = fmaxf(mx, __shfl_xor(mx, off));
        float e = __expf(lg - mx);
        float sm = e;
        for (int off = 8; off; off >>= 1) sm += __shfl_xor(sm, off);
        float p = e / sm;

        float4 ai = f4zero();
        int gbase = lane & 48;
#pragma unroll
        for (int tk = 0; tk < 16; ++tk) {
            float pk = __shfl(p, gbase + tk);
            ai = f4fma(pk, *(float4*)&vlR[tk * 68 + 4 * u], ai);
        }

        if (it == 0) {
            ai0 = ai;
        } else if (it == 1) {
            dlocal = fabsf(ai.x - ai0.x) + fabsf(ai.y - ai0.y) +
                     fabsf(ai.z - ai0.z) + fabsf(ai.w - ai0.w);
            *(float4*)&ai1g[rowi2 * 1024 + col2] = ai;
        } else {
            *(float4*)&ai2g[rowi2 * 1024 + col2] = ai;
        }
        qcT[(4 * u + 0) * 20 + t2] += ai.x;
        qcT[(4 * u + 1) * 20 + t2] += ai.y;
        qcT[(4 * u + 2) * 20 + t2] += ai.z;
        qcT[(4 * u + 3) * 20 + t2] += ai.w;
        __syncthreads();
    }

    float ds = dlocal;
    for (int off = 32; off; off >>= 1) ds += __shfl_xor(ds, off);
    if (lane == 0) dred[wv] = ds;
    __syncthreads();
    if (tid == 0) atomicAdd(diffg, dred[0] + dred[1] + dred[2] + dred[3]);
}

// ---------------- K4: ai_sel @ Wo^T, split-K partials ----------------
__global__ __launch_bounds__(256) void k_wo(const float* __restrict__ ai1g,
                                            const float* __restrict__ ai2g,
                                            const float* __restrict__ diffg,
                                            const float* __restrict__ thrp,
                                            const float* __restrict__ facp,
                                            const float* __restrict__ Wo,
                                            float* __restrict__ wop) {
    float diff = diffg[0] * (1.0f / 8388608.0f);
    const float* A = (diff < thrp[0] + facp[0] * diff) ? ai1g : ai2g;
    int jt  = blockIdx.x;
    int ksl = blockIdx.y;
    int k0  = ksl * 128;
    __shared__ float At[64][132];
    __shared__ float Bt[32][132];
    int tid = threadIdx.x;
    for (int i = tid; i < 2048; i += 256) {
        int r = i >> 5, kk = (i & 31) << 2;
        *(float4*)&At[r][kk] = *(const float4*)&A[r * 1024 + k0 + kk];
    }
    for (int i = tid; i < 1024; i += 256) {
        int r = i >> 5, kk = (i & 31) << 2;
        *(float4*)&Bt[r][kk] = *(const float4*)&Wo[(size_t)(jt * 32 + r) * 1024 + k0 + kk];
    }
    __syncthreads();
    int rg = tid >> 4, cg = tid & 15;
    float acc[4][2];
#pragma unroll
    for (int i = 0; i < 4; i++) { acc[i][0] = 0.f; acc[i][1] = 0.f; }
    for (int k = 0; k < 128; k += 4) {
        float4 b0 = *(float4*)&Bt[cg * 2 + 0][k];
        float4 b1 = *(float4*)&Bt[cg * 2 + 1][k];
#pragma unroll
        for (int i = 0; i < 4; i++) {
            float4 a = *(float4*)&At[rg * 4 + i][k];
            acc[i][0] = dot4acc(a, b0, acc[i][0]);
            acc[i][1] = dot4acc(a, b1, acc[i][1]);
        }
    }
    float* dst = wop + (size_t)ksl * 65536;
    int colg = jt * 32 + cg * 2;
#pragma unroll
    for (int i = 0; i < 4; i++) {
        *(float2*)&dst[(rg * 4 + i) * 1024 + colg] = make_float2(acc[i][0], acc[i][1]);
    }
}

// ---------------- K5: final output write ----------------
__global__ __launch_bounds__(256) void k_bo(const float* __restrict__ bo,
                                            const float* __restrict__ wop,
                                            float* __restrict__ out) {
    int row = blockIdx.x;
    int tid = threadIdx.x;
    int b = row >> 11, t = row & 2047;
    float4 o = *(const float4*)&bo[tid * 4];
    if (t < 16) {
        int ri = b * 16 + t;
#pragma unroll
        for (int s = 0; s < 8; s++) {
            float4 p = *(const float4*)&wop[(size_t)s * 65536 + ri * 1024 + tid * 4];
            o = f4add(o, p);
        }
    }
    *(float4*)&out[(size_t)row * 1024 + tid * 4] = o;
}

extern "C" void kernel_launch(void* const* d_in, const int* in_sizes, int n_in,
                              void* d_out, int out_size, void* d_ws, size_t ws_size,
                              hipStream_t stream) {
    (void)in_sizes; (void)n_in; (void)out_size; (void)ws_size;
    const float* x    = (const float*)d_in[0];
    const float* Wq   = (const float*)d_in[1];
    const float* bq   = (const float*)d_in[2];
    const float* Wk   = (const float*)d_in[3];
    const float* Wv   = (const float*)d_in[4];
    const float* bv   = (const float*)d_in[5];
    const float* Wo   = (const float*)d_in[6];
    const float* bo   = (const float*)d_in[7];
    const float* lna  = (const float*)d_in[8];
    const float* lnc  = (const float*)d_in[9];
    const float* lnd  = (const float*)d_in[10];
    const float* Wlq  = (const float*)d_in[11];
    const float* blq  = (const float*)d_in[12];
    const float* Wlk  = (const float*)d_in[13];
    const float* blk_ = (const float*)d_in[14];
    const float* Wlv  = (const float*)d_in[15];
    const float* blv  = (const float*)d_in[16];
    const float* temp = (const float*)d_in[17];
    const float* thr  = (const float*)d_in[18];
    const float* fac  = (const float*)d_in[19];
    float* ws  = (float*)d_ws;
    float* out = (float*)d_out;

    k_ln  <<<67, 256, 0, stream>>>(x, lna, Wlq, Wlk, Wlv,
                                   ws + WS_XN, ws + WS_WT, ws + WS_DIFF);
    k_qkv <<<dim3(96, 8), 256, 0, stream>>>(ws + WS_XN, Wq, Wk, Wv, ws + WS_QKVP);
    k_iter<<<64, 256, 0, stream>>>(ws + WS_QKVP, ws + WS_WT, bq, bv, lnc, lnd,
                                   blq, blk_, blv, temp,
                                   ws + WS_AI1, ws + WS_AI2, ws + WS_DIFF);
    k_wo  <<<dim3(32, 8), 256, 0, stream>>>(ws + WS_AI1, ws + WS_AI2, ws + WS_DIFF,
                                            thr, fac, Wo, ws + WS_WOP);
    k_bo  <<<8192, 256, 0, stream>>>(bo, ws + WS_WOP, out);
}

// Round 8
// 159.209 us; speedup vs baseline: 1.4019x; 1.0065x over previous
//
#include <hip/hip_runtime.h>
#include <math.h>

// ---------------- workspace layout (float offsets) ----------------
// Only the first 16 tokens per batch matter (E = HEAD = 16 slices the T axis).
#define WS_XN    0          // 64*1024                  LN'd x rows
#define WS_QKVP  65536      // 8 * 64*3072              split-K partials of q|k|v
#define WS_DIFF  1638400    // 1                        sum |ai1-ai0|
#define WS_AI1   1638404    // 64*1024                  iter-1 attention out
#define WS_AI2   1703940    // 64*1024                  iter-2 attention out
#define WS_WOP   1769476    // 8 * 64*1024              split-K partials of ai_sel @ Wo^T
#define WS_WT    2293764    // 3 * 4096                 WlqT|WlkT|WlvT  ([k][d] layout)
// end: 2306052 floats = ~9.2 MB

__device__ __forceinline__ float4 f4zero() { return make_float4(0.f, 0.f, 0.f, 0.f); }
__device__ __forceinline__ float4 f4add(float4 a, float4 b) {
    return make_float4(a.x + b.x, a.y + b.y, a.z + b.z, a.w + b.w);
}
__device__ __forceinline__ float4 f4fma(float s, float4 a, float4 c) {
    return make_float4(fmaf(s, a.x, c.x), fmaf(s, a.y, c.y),
                       fmaf(s, a.z, c.z), fmaf(s, a.w, c.w));
}
__device__ __forceinline__ float dot4acc(float4 a, float4 b, float acc) {
    acc = fmaf(a.x, b.x, acc); acc = fmaf(a.y, b.y, acc);
    acc = fmaf(a.z, b.z, acc); acc = fmaf(a.w, b.w, acc);
    return acc;
}

// 16x64 @ 64x64 GEMM, both operands in LDS. A: [k][t] stride 20 (broadcast
// reads). W: [k][d] stride 64 (16 distinct float4/wave -> 2-way banks, free).
__device__ __forceinline__ void gemm_lds(const float* __restrict__ ldsA, int tq,
                                         const float* __restrict__ ldsW, int dq,
                                         float acc[4][4]) {
#pragma unroll 8
    for (int k = 0; k < 64; ++k) {
        float4 a4 = *(const float4*)&ldsA[k * 20 + 4 * tq];
        float4 b4 = *(const float4*)&ldsW[k * 64 + 4 * dq];
        float av[4] = { a4.x, a4.y, a4.z, a4.w };
#pragma unroll
        for (int i = 0; i < 4; i++) {
            acc[i][0] = fmaf(av[i], b4.x, acc[i][0]);
            acc[i][1] = fmaf(av[i], b4.y, acc[i][1]);
            acc[i][2] = fmaf(av[i], b4.z, acc[i][2]);
            acc[i][3] = fmaf(av[i], b4.w, acc[i][3]);
        }
    }
}

// ---------------- K1: LayerNorm of 64 rows + weight transpose ----------------
__global__ __launch_bounds__(256) void k_ln(const float* __restrict__ x,
                                            const float* __restrict__ lna,
                                            const float* __restrict__ Wlq,
                                            const float* __restrict__ Wlk,
                                            const float* __restrict__ Wlv,
                                            float* __restrict__ xn,
                                            float* __restrict__ wt,
                                            float* __restrict__ diffg) {
    if (blockIdx.x >= 64) {
        int m = blockIdx.x - 64;
        const float* W = (m == 0) ? Wlq : (m == 1) ? Wlk : Wlv;
        float* dst = wt + m * 4096;
        for (int i = threadIdx.x; i < 4096; i += 256) {
            int k = i >> 6, d = i & 63;
            dst[i] = W[d * 64 + k];
        }
        return;
    }
    int r = blockIdx.x;                 // 0..63 = b*16 + t
    int b = r >> 4, t = r & 15;
    if (blockIdx.x == 0 && threadIdx.x == 0) diffg[0] = 0.f;
    const float* row = x + (size_t)(b * 2048 + t) * 1024;
    int tid = threadIdx.x;
    float4 xv = *(const float4*)&row[tid * 4];
    float s1 = xv.x + xv.y + xv.z + xv.w;
    float s2 = xv.x * xv.x + xv.y * xv.y + xv.z * xv.z + xv.w * xv.w;
    for (int off = 32; off; off >>= 1) {
        s1 += __shfl_xor(s1, off);
        s2 += __shfl_xor(s2, off);
    }
    __shared__ float ssum[4], ssq[4];
    int wv = tid >> 6, lane = tid & 63;
    if (lane == 0) { ssum[wv] = s1; ssq[wv] = s2; }
    __syncthreads();
    float tot = ssum[0] + ssum[1] + ssum[2] + ssum[3];
    float tq  = ssq[0] + ssq[1] + ssq[2] + ssq[3];
    float m   = tot * (1.0f / 1024.0f);
    float var = tq * (1.0f / 1024.0f) - m * m;
    float rs  = rsqrtf(var + 1e-5f);
    float4 w4 = *(const float4*)&lna[tid * 4];
    float4 o  = make_float4((xv.x - m) * rs * w4.x, (xv.y - m) * rs * w4.y,
                            (xv.z - m) * rs * w4.z, (xv.w - m) * rs * w4.w);
    *(float4*)&xn[r * 1024 + tid * 4] = o;
}

// ---------------- K2: q|k|v = xn @ [Wq|Wk|Wv]^T, split-K partials ----------------
__global__ __launch_bounds__(256) void k_qkv(const float* __restrict__ xn,
                                             const float* __restrict__ Wq,
                                             const float* __restrict__ Wk,
                                             const float* __restrict__ Wv,
                                             float* __restrict__ qkvp) {
    int ct  = blockIdx.x;               // 0..95
    int ksl = blockIdx.y;               // 0..7
    int m   = ct >> 5;
    const float* W = (m == 0) ? Wq : (m == 1) ? Wk : Wv;
    int j0 = (ct & 31) * 32;
    int k0 = ksl * 128;
    __shared__ float At[64][132];
    __shared__ float Bt[32][132];
    int tid = threadIdx.x;
    for (int i = tid; i < 2048; i += 256) {
        int r = i >> 5, kk = (i & 31) << 2;
        *(float4*)&At[r][kk] = *(const float4*)&xn[r * 1024 + k0 + kk];
    }
    for (int i = tid; i < 1024; i += 256) {
        int r = i >> 5, kk = (i & 31) << 2;
        *(float4*)&Bt[r][kk] = *(const float4*)&W[(size_t)(j0 + r) * 1024 + k0 + kk];
    }
    __syncthreads();
    int rg = tid >> 4, cg = tid & 15;
    float acc[4][2];
#pragma unroll
    for (int i = 0; i < 4; i++) { acc[i][0] = 0.f; acc[i][1] = 0.f; }
    for (int k = 0; k < 128; k += 4) {
        float4 b0 = *(float4*)&Bt[cg * 2 + 0][k];
        float4 b1 = *(float4*)&Bt[cg * 2 + 1][k];
#pragma unroll
        for (int i = 0; i < 4; i++) {
            float4 a = *(float4*)&At[rg * 4 + i][k];
            acc[i][0] = dot4acc(a, b0, acc[i][0]);
            acc[i][1] = dot4acc(a, b1, acc[i][1]);
        }
    }
    float* dst = qkvp + (size_t)ksl * 196608;
    int colg = ct * 32 + cg * 2;
#pragma unroll
    for (int i = 0; i < 4; i++) {
        *(float2*)&dst[(rg * 4 + i) * 3072 + colg] = make_float2(acc[i][0], acc[i][1]);
    }
}

// ---------------- K3: fold + 3-iteration loop + overlapped bo-broadcast ------
// Blocks 0..63: one per (b,h), weights in LDS (48 KB), fused split-K fold.
// Blocks 64..8191: pure bo-broadcast writes for the 8128 non-real output rows
// (no LDS/barrier use) -- they overlap the compute blocks' ~10 us on the other
// 192 CUs, hiding the mandatory 33 MB output write. LDS ~78 KB -> 2 blocks/CU.
__global__ __launch_bounds__(256, 2) void k_iter(
        const float* __restrict__ qkvp, const float* __restrict__ wt,
        const float* __restrict__ bq,  const float* __restrict__ bv,
        const float* __restrict__ lnc, const float* __restrict__ lnd,
        const float* __restrict__ blq, const float* __restrict__ blk_,
        const float* __restrict__ blv, const float* __restrict__ temp,
        const float* __restrict__ bo,  float* __restrict__ out,
        float* __restrict__ ai1g, float* __restrict__ ai2g,
        float* __restrict__ diffg) {
    __shared__ __align__(16) float wS[12288];      // WlqT|WlkT|WlvT ([k][d])
    __shared__ __align__(16) float qcT[64 * 20];   // [d-or-k][t] stride 20
    __shared__ __align__(16) float kcT[64 * 20];
    __shared__ __align__(16) float vcT[64 * 20];
    __shared__ __align__(16) float qsR[16 * 68];   // row-major [t][d]
    __shared__ __align__(16) float ksR[16 * 68];
    __shared__ __align__(16) float vlR[16 * 68];
    __shared__ float dred[4];

    int tid  = threadIdx.x;

    if (blockIdx.x >= 64) {              // ---- bo-broadcast blocks ----
        int i2 = blockIdx.x - 64;        // 0..8127
        int bb = i2 / 2032;              // 0..3
        int tt = 16 + (i2 - bb * 2032);  // 16..2047
        float4 o = *(const float4*)&bo[tid * 4];
        *(float4*)&out[(size_t)(bb * 2048 + tt) * 1024 + tid * 4] = o;
        return;
    }

    int b    = blockIdx.x >> 4, h = blockIdx.x & 15;
    int wv   = tid >> 6, lane = tid & 63;
    float tempv = temp[0];

    int tq = lane >> 4, dq = lane & 15;     // P1 tile coords
    int t2 = tid >> 4,  u  = tid & 15;      // P2 coords
    int rowi2 = b * 16 + t2, col2 = h * 64 + u * 4;

    // ---- weight staging: 12 float4 per thread, independent, pipelined
#pragma unroll
    for (int j = 0; j < 12; ++j) {
        int idx = (tid + j * 256) * 4;
        *(float4*)&wS[idx] = *(const float4*)&wt[idx];
    }

    // ---- fused split-K fold + scale/bias + transposed state staging
    float4 qreg;                                    // qcur[t2][4u..] in register
    {
        const float SCALE = 0.35355339059327378f;   // 64^-0.25
        const float* P = qkvp + rowi2 * 3072 + col2;
        float4 q4 = f4zero(), k4 = f4zero(), v4 = f4zero();
#pragma unroll
        for (int sl = 0; sl < 8; sl++) {
            const float* Ps = P + (size_t)sl * 196608;
            q4 = f4add(q4, *(const float4*)&Ps[0]);
            k4 = f4add(k4, *(const float4*)&Ps[1024]);
            v4 = f4add(v4, *(const float4*)&Ps[2048]);
        }
        float4 bq4 = *(const float4*)&bq[col2];
        float4 bv4 = *(const float4*)&bv[col2];
        qreg = make_float4((q4.x + bq4.x) * SCALE, (q4.y + bq4.y) * SCALE,
                           (q4.z + bq4.z) * SCALE, (q4.w + bq4.w) * SCALE);
        float kv[4] = { k4.x * SCALE, k4.y * SCALE, k4.z * SCALE, k4.w * SCALE };
        float vv[4] = { v4.x + bv4.x, v4.y + bv4.y, v4.z + bv4.z, v4.w + bv4.w };
        float qv[4] = { qreg.x, qreg.y, qreg.z, qreg.w };
#pragma unroll
        for (int c = 0; c < 4; c++) {
            qcT[(u * 4 + c) * 20 + t2] = qv[c];
            kcT[(u * 4 + c) * 20 + t2] = kv[c];
            vcT[(u * 4 + c) * 20 + t2] = vv[c];
        }
    }
    __syncthreads();

    float4 ai0 = f4zero();
    float  dlocal = 0.f;

#pragma unroll 1
    for (int it = 0; it < 3; ++it) {
        float t_it = tempv + 0.005f * (float)it;
        float tsc  = (t_it != 1.0f && t_it > 0.0f) ? rsqrtf(t_it) : 1.0f;

        // ---------------- P1: three GEMMs, wave-specialized ----------------
        if (wv == 0) {
            float acc[4][4];
#pragma unroll
            for (int i = 0; i < 4; i++)
#pragma unroll
                for (int j = 0; j < 4; j++) acc[i][j] = 0.f;
            gemm_lds(qcT, tq, wS, dq, acc);
            float4 bb = *(const float4*)&blq[4 * dq];
            float4 lw = *(const float4*)&lnc[4 * dq];
#pragma unroll
            for (int i = 0; i < 4; i++) {
                acc[i][0] += bb.x; acc[i][1] += bb.y;
                acc[i][2] += bb.z; acc[i][3] += bb.w;
                float s1 = acc[i][0] + acc[i][1] + acc[i][2] + acc[i][3];
                float s2 = acc[i][0]*acc[i][0] + acc[i][1]*acc[i][1]
                         + acc[i][2]*acc[i][2] + acc[i][3]*acc[i][3];
                for (int off = 8; off; off >>= 1) {
                    s1 += __shfl_xor(s1, off); s2 += __shfl_xor(s2, off);
                }
                float m  = s1 * (1.0f / 64.0f);
                float vr = s2 * (1.0f / 64.0f) - m * m;
                float rs = rsqrtf(vr + 1e-5f) * tsc;
                float4 o = make_float4((acc[i][0] - m) * rs * lw.x,
                                       (acc[i][1] - m) * rs * lw.y,
                                       (acc[i][2] - m) * rs * lw.z,
                                       (acc[i][3] - m) * rs * lw.w);
                *(float4*)&qsR[(4 * tq + i) * 68 + 4 * dq] = o;
            }
        } else if (wv == 1) {
            float acc[4][4];
#pragma unroll
            for (int i = 0; i < 4; i++)
#pragma unroll
                for (int j = 0; j < 4; j++) acc[i][j] = 0.f;
            gemm_lds(kcT, tq, wS + 4096, dq, acc);
            float4 bb = *(const float4*)&blk_[4 * dq];
#pragma unroll
            for (int i = 0; i < 4; i++) {
                acc[i][0] += bb.x; acc[i][1] += bb.y;
                acc[i][2] += bb.z; acc[i][3] += bb.w;
            }
            if (it < 2) {                       // kcur_next dead after last iter
#pragma unroll
                for (int j = 0; j < 4; j++) {
                    float4 cv = make_float4(acc[0][j], acc[1][j], acc[2][j], acc[3][j]);
                    *(float4*)&kcT[(4 * dq + j) * 20 + 4 * tq] = cv;
                }
            }
            float4 lw = *(const float4*)&lnd[4 * dq];
#pragma unroll
            for (int i = 0; i < 4; i++) {
                float s1 = acc[i][0] + acc[i][1] + acc[i][2] + acc[i][3];
                float s2 = acc[i][0]*acc[i][0] + acc[i][1]*acc[i][1]
                         + acc[i][2]*acc[i][2] + acc[i][3]*acc[i][3];
                for (int off = 8; off; off >>= 1) {
                    s1 += __shfl_xor(s1, off); s2 += __shfl_xor(s2, off);
                }
                float m  = s1 * (1.0f / 64.0f);
                float vr = s2 * (1.0f / 64.0f) - m * m;
                float rs = rsqrtf(vr + 1e-5f);
                float4 o = make_float4((acc[i][0] - m) * rs * lw.x,
                                       (acc[i][1] - m) * rs * lw.y,
                                       (acc[i][2] - m) * rs * lw.z,
                                       (acc[i][3] - m) * rs * lw.w);
                *(float4*)&ksR[(4 * tq + i) * 68 + 4 * dq] = o;
            }
        } else if (wv == 2) {
            float acc[4][4];
#pragma unroll
            for (int i = 0; i < 4; i++)
#pragma unroll
                for (int j = 0; j < 4; j++) acc[i][j] = 0.f;
            gemm_lds(vcT, tq, wS + 8192, dq, acc);
            float4 bb = *(const float4*)&blv[4 * dq];
#pragma unroll
            for (int i = 0; i < 4; i++) {
                acc[i][0] += bb.x; acc[i][1] += bb.y;
                acc[i][2] += bb.z; acc[i][3] += bb.w;
                *(float4*)&vlR[(4 * tq + i) * 68 + 4 * dq] =
                    make_float4(acc[i][0], acc[i][1], acc[i][2], acc[i][3]);
            }
            if (it < 2) {                       // vcur_next dead after last iter
#pragma unroll
                for (int j = 0; j < 4; j++) {
                    float4 cv = make_float4(acc[0][j], acc[1][j], acc[2][j], acc[3][j]);
                    *(float4*)&vcT[(4 * dq + j) * 20 + 4 * tq] = cv;
                }
            }
        }
        __syncthreads();

        // ---------------- P2: logits + softmax + P@vl (all waves) ----------
        float lg = 0.f;
#pragma unroll
        for (int c = 0; c < 16; ++c) {
            float4 a4 = *(float4*)&qsR[t2 * 68 + 4 * c];
            float4 b4 = *(float4*)&ksR[u  * 68 + 4 * c];
            lg = dot4acc(a4, b4, lg);
        }
        lg *= 0.125f;                        // 1/sqrt(64)
        float mx = lg;
        for (int off = 8; off; off >>= 1) mx = fmaxf(mx, __shfl_xor(mx, off));
        float e = __expf(lg - mx);
        float sm = e;
        for (int off = 8; off; off >>= 1) sm += __shfl_xor(sm, off);
        float p = e / sm;

        float4 ai = f4zero();
        int gbase = lane & 48;
#pragma unroll
        for (int tk = 0; tk < 16; ++tk) {
            float pk = __shfl(p, gbase + tk);
            ai = f4fma(pk, *(float4*)&vlR[tk * 68 + 4 * u], ai);
        }

        if (it == 0) {
            ai0 = ai;
        } else if (it == 1) {
            dlocal = fabsf(ai.x - ai0.x) + fabsf(ai.y - ai0.y) +
                     fabsf(ai.z - ai0.z) + fabsf(ai.w - ai0.w);
            *(float4*)&ai1g[rowi2 * 1024 + col2] = ai;
        } else {
            *(float4*)&ai2g[rowi2 * 1024 + col2] = ai;
        }
        if (it < 2) {                        // qcur += ai (register; 4 LDS writes)
            qreg = f4add(qreg, ai);
            qcT[(4 * u + 0) * 20 + t2] = qreg.x;
            qcT[(4 * u + 1) * 20 + t2] = qreg.y;
            qcT[(4 * u + 2) * 20 + t2] = qreg.z;
            qcT[(4 * u + 3) * 20 + t2] = qreg.w;
        }
        __syncthreads();
    }

    float ds = dlocal;
    for (int off = 32; off; off >>= 1) ds += __shfl_xor(ds, off);
    if (lane == 0) dred[wv] = ds;
    __syncthreads();
    if (tid == 0) atomicAdd(diffg, dred[0] + dred[1] + dred[2] + dred[3]);
}

// ---------------- K4: ai_sel @ Wo^T, split-K partials ----------------
__global__ __launch_bounds__(256) void k_wo(const float* __restrict__ ai1g,
                                            const float* __restrict__ ai2g,
                                            const float* __restrict__ diffg,
                                            const float* __restrict__ thrp,
                                            const float* __restrict__ facp,
                                            const float* __restrict__ Wo,
                                            float* __restrict__ wop) {
    float diff = diffg[0] * (1.0f / 8388608.0f);
    const float* A = (diff < thrp[0] + facp[0] * diff) ? ai1g : ai2g;
    int jt  = blockIdx.x;
    int ksl = blockIdx.y;
    int k0  = ksl * 128;
    __shared__ float At[64][132];
    __shared__ float Bt[32][132];
    int tid = threadIdx.x;
    for (int i = tid; i < 2048; i += 256) {
        int r = i >> 5, kk = (i & 31) << 2;
        *(float4*)&At[r][kk] = *(const float4*)&A[r * 1024 + k0 + kk];
    }
    for (int i = tid; i < 1024; i += 256) {
        int r = i >> 5, kk = (i & 31) << 2;
        *(float4*)&Bt[r][kk] = *(const float4*)&Wo[(size_t)(jt * 32 + r) * 1024 + k0 + kk];
    }
    __syncthreads();
    int rg = tid >> 4, cg = tid & 15;
    float acc[4][2];
#pragma unroll
    for (int i = 0; i < 4; i++) { acc[i][0] = 0.f; acc[i][1] = 0.f; }
    for (int k = 0; k < 128; k += 4) {
        float4 b0 = *(float4*)&Bt[cg * 2 + 0][k];
        float4 b1 = *(float4*)&Bt[cg * 2 + 1][k];
#pragma unroll
        for (int i = 0; i < 4; i++) {
            float4 a = *(float4*)&At[rg * 4 + i][k];
            acc[i][0] = dot4acc(a, b0, acc[i][0]);
            acc[i][1] = dot4acc(a, b1, acc[i][1]);
        }
    }
    float* dst = wop + (size_t)ksl * 65536;
    int colg = jt * 32 + cg * 2;
#pragma unroll
    for (int i = 0; i < 4; i++) {
        *(float2*)&dst[(rg * 4 + i) * 1024 + colg] = make_float2(acc[i][0], acc[i][1]);
    }
}

// ---------------- K5: final output write, real rows only ----------------
__global__ __launch_bounds__(256) void k_bo(const float* __restrict__ bo,
                                            const float* __restrict__ wop,
                                            float* __restrict__ out) {
    int ri  = blockIdx.x;               // 0..63 = b*16 + t
    int tid = threadIdx.x;
    int b = ri >> 4, t = ri & 15;
    float4 o = *(const float4*)&bo[tid * 4];
#pragma unroll
    for (int s = 0; s < 8; s++) {
        float4 p = *(const float4*)&wop[(size_t)s * 65536 + ri * 1024 + tid * 4];
        o = f4add(o, p);
    }
    *(float4*)&out[(size_t)(b * 2048 + t) * 1024 + tid * 4] = o;
}

extern "C" void kernel_launch(void* const* d_in, const int* in_sizes, int n_in,
                              void* d_out, int out_size, void* d_ws, size_t ws_size,
                              hipStream_t stream) {
    (void)in_sizes; (void)n_in; (void)out_size; (void)ws_size;
    const float* x    = (const float*)d_in[0];
    const float* Wq   = (const float*)d_in[1];
    const float* bq   = (const float*)d_in[2];
    const float* Wk   = (const float*)d_in[3];
    const float* Wv   = (const float*)d_in[4];
    const float* bv   = (const float*)d_in[5];
    const float* Wo   = (const float*)d_in[6];
    const float* bo   = (const float*)d_in[7];
    const float* lna  = (const float*)d_in[8];
    const float* lnc  = (const float*)d_in[9];
    const float* lnd  = (const float*)d_in[10];
    const float* Wlq  = (const float*)d_in[11];
    const float* blq  = (const float*)d_in[12];
    const float* Wlk  = (const float*)d_in[13];
    const float* blk_ = (const float*)d_in[14];
    const float* Wlv  = (const float*)d_in[15];
    const float* blv  = (const float*)d_in[16];
    const float* temp = (const float*)d_in[17];
    const float* thr  = (const float*)d_in[18];
    const float* fac  = (const float*)d_in[19];
    float* ws  = (float*)d_ws;
    float* out = (float*)d_out;

    k_ln  <<<67, 256, 0, stream>>>(x, lna, Wlq, Wlk, Wlv,
                                   ws + WS_XN, ws + WS_WT, ws + WS_DIFF);
    k_qkv <<<dim3(96, 8), 256, 0, stream>>>(ws + WS_XN, Wq, Wk, Wv, ws + WS_QKVP);
    k_iter<<<64 + 8128, 256, 0, stream>>>(ws + WS_QKVP, ws + WS_WT, bq, bv,
                                          lnc, lnd, blq, blk_, blv, temp,
                                          bo, out,
                                          ws + WS_AI1, ws + WS_AI2, ws + WS_DIFF);
    k_wo  <<<dim3(32, 8), 256, 0, stream>>>(ws + WS_AI1, ws + WS_AI2, ws + WS_DIFF,
                                            thr, fac, Wo, ws + WS_WOP);
    k_bo  <<<64, 256, 0, stream>>>(bo, ws + WS_WOP, out);
}